// Round 2
// baseline (424.410 us; speedup 1.0000x reference)
//
#include <hip/hip_runtime.h>

#define DI static __device__ __forceinline__

typedef __attribute__((ext_vector_type(8))) short s8v;
typedef __attribute__((ext_vector_type(4))) float f4v;

DI short f2b(float x) {
  unsigned u = __builtin_bit_cast(unsigned, x);
  u = (u + 0x7fffu + ((u >> 16) & 1u)) >> 16;
  return (short)u;
}
DI float b2f(short s) {
  unsigned u = ((unsigned)(unsigned short)s) << 16;
  return __builtin_bit_cast(float, u);
}
DI f4v mfma16(s8v a, s8v b, f4v c) {
  return __builtin_amdgcn_mfma_f32_16x16x32_bf16(a, b, c, 0, 0, 0);
}

// ---------------- f32 -> bf16 convert ----------------
__global__ __launch_bounds__(256) void cvt_k(const float* __restrict__ src,
                                             short* __restrict__ dst, int n) {
  int i = blockIdx.x * 256 + threadIdx.x;
  if (i < n) dst[i] = f2b(src[i]);
}

// ---------------- grouped 9x9 stride-2 conv (offset net part 1) ----------------
// out: co[n=128][s=128][c=320] fp32, bias added
__global__ __launch_bounds__(256) void conv_off_k(
    const float* __restrict__ x, const float* __restrict__ y,
    const float* __restrict__ w1, const float* __restrict__ b1,
    float* __restrict__ co)
{
  __shared__ float si[8][16][72];   // 8 ch, rows -4..11, cols -4..67 (zero padded)
  __shared__ float sw[8][2][81];
  const int cc = blockIdx.x;        // channel chunk (8 ch)
  const int n  = blockIdx.y;        // b*4+g
  const int b = n >> 2, g = n & 3;
  const int c0 = cc * 8;
  const float* src = (g < 2 ? x : y) + ((size_t)b * 640 + (g & 1) * 320 + c0) * 512;
  const int tid = threadIdx.x;
  for (int i = tid; i < 8 * 16 * 72; i += 256) ((float*)si)[i] = 0.f;
  __syncthreads();
  for (int i = tid; i < 8 * 8 * 64; i += 256) {
    int ch = i >> 9, r = (i >> 6) & 7, col = i & 63;
    si[ch][r + 4][col + 4] = src[(size_t)(ch * 8 + r) * 64 + col];
  }
  for (int i = tid; i < 8 * 162; i += 256)
    ((float*)sw)[i] = w1[(size_t)c0 * 162 + i];
  __syncthreads();

  const int lane = tid & 63, wvi = tid >> 6;
  const int wk = lane & 31, hk0 = lane >> 5, hk1 = hk0 + 2;
#pragma unroll
  for (int oo = 0; oo < 2; ++oo) {
    int oc = wvi * 2 + oo;
    int icb = oc & ~1;
    float a0 = 0.f, a1 = 0.f;
#pragma unroll
    for (int ic = 0; ic < 2; ++ic) {
      const float* wv = &sw[oc][ic][0];
      const float* p0 = &si[icb + ic][hk0 * 2][wk * 2];
      const float* p1 = &si[icb + ic][hk1 * 2][wk * 2];
#pragma unroll
      for (int kh = 0; kh < 9; ++kh) {
#pragma unroll
        for (int kw2 = 0; kw2 < 9; ++kw2) {
          float wt = wv[kh * 9 + kw2];
          a0 = fmaf(p0[kh * 72 + kw2], wt, a0);
          a1 = fmaf(p1[kh * 72 + kw2], wt, a1);
        }
      }
    }
    float bv = b1[c0 + oc];
    co[((size_t)n * 128 + hk0 * 32 + wk) * 320 + c0 + oc] = a0 + bv;
    co[((size_t)n * 128 + hk1 * 32 + wk) * 320 + c0 + oc] = a1 + bv;
  }
}

// ---------------- LN + GELU + proj + tanh -> pos (offset net part 2) ----------------
__global__ __launch_bounds__(320) void ln_proj_k(
    const float* __restrict__ co, const float* __restrict__ lng,
    const float* __restrict__ lnb, const float* __restrict__ w2,
    float* __restrict__ pos, float* __restrict__ pos_out, float* __restrict__ ref_out)
{
  const int s = blockIdx.x, n = blockIdx.y;
  const int tid = threadIdx.x;
  __shared__ float rA[8], rB[8];
  float v = co[((size_t)n * 128 + s) * 320 + tid];
  float a = v, b2 = v * v;
#pragma unroll
  for (int o = 32; o; o >>= 1) { a += __shfl_xor(a, o); b2 += __shfl_xor(b2, o); }
  int wid = tid >> 6;
  if ((tid & 63) == 0) { rA[wid] = a; rB[wid] = b2; }
  __syncthreads();
  if (tid == 0) {
    float s1 = 0.f, s2 = 0.f;
    for (int i = 0; i < 5; ++i) { s1 += rA[i]; s2 += rB[i]; }
    rA[6] = s1; rB[6] = s2;
  }
  __syncthreads();
  float mu = rA[6] * (1.f / 320.f);
  float var = rB[6] * (1.f / 320.f) - mu * mu;
  float xn = (v - mu) * rsqrtf(var + 1e-5f) * lng[tid] + lnb[tid];
  float ge = 0.5f * xn * (1.f + erff(xn * 0.70710678118654752f));
  float d0 = ge * w2[tid], d1 = ge * w2[320 + tid];
#pragma unroll
  for (int o = 32; o; o >>= 1) { d0 += __shfl_xor(d0, o); d1 += __shfl_xor(d1, o); }
  __syncthreads();
  if ((tid & 63) == 0) { rA[wid] = d0; rB[wid] = d1; }
  __syncthreads();
  if (tid == 0) {
    float D0 = 0.f, D1 = 0.f;
    for (int i = 0; i < 5; ++i) { D0 += rA[i]; D1 += rB[i]; }
    float oy = tanhf(D0) * 0.5f;      // (1/Hk)*ORF = 2/4
    float ox = tanhf(D1) * 0.0625f;   // (1/Wk)*ORF = 2/32
    int hk = s >> 5, wk = s & 31;
    float ry = ((float)hk + 0.5f) * 0.5f - 1.f;
    float rx = ((float)wk + 0.5f) * 0.0625f - 1.f;
    float py = oy + ry, px = ox + rx;
    size_t o2 = ((size_t)n * 128 + s) * 2;
    pos[o2] = py;     pos[o2 + 1] = px;
    pos_out[o2] = py; pos_out[o2 + 1] = px;
    ref_out[o2] = ry; ref_out[o2 + 1] = rx;
  }
}

// ---------------- transpose x [b][c][hw] f32 -> xt [b][hw][c] bf16 ----------------
__global__ __launch_bounds__(256) void transpose_k(const float* __restrict__ x,
                                                   short* __restrict__ xt) {
  __shared__ float tile[32][33];
  const int ct = blockIdx.x, st = blockIdx.y, b = blockIdx.z;
  const int tx = threadIdx.x, ty = threadIdx.y;
  const float* src = x + ((size_t)b * 640 + ct * 32) * 512 + st * 32;
#pragma unroll
  for (int k2 = 0; k2 < 4; ++k2)
    tile[ty + 8 * k2][tx] = src[(size_t)(ty + 8 * k2) * 512 + tx];
  __syncthreads();
  short* dst = xt + ((size_t)b * 512 + st * 32) * 640 + ct * 32;
#pragma unroll
  for (int k2 = 0; k2 < 4; ++k2)
    dst[(size_t)(ty + 8 * k2) * 640 + tx] = f2b(tile[tx][ty + 8 * k2]);
}

// ---------------- bilinear sampler: xs[b][n=128][c=640] bf16 ----------------
__global__ __launch_bounds__(256) void sample_k(const short* __restrict__ xt,
                                                const float* __restrict__ pos,
                                                short* __restrict__ xs) {
  const int sc = blockIdx.x, bg = blockIdx.y;
  const int b = bg >> 2, g = bg & 3;
  const int t = threadIdx.x;
  const int s = sc * 8 + (t >> 5);
  const int ci = t & 31;
  size_t p2 = ((size_t)bg * 128 + s) * 2;
  float py = pos[p2], px = pos[p2 + 1];
  float gx = (px + 1.f) * 32.f - 0.5f;   // Wi=64
  float gy = (py + 1.f) * 4.f - 0.5f;    // Hi=8
  float fx = floorf(gx), fy = floorf(gy);
  int x0 = (int)fx, y0 = (int)fy;
  float wx1 = gx - fx, wx0 = 1.f - wx1;
  float wy1 = gy - fy, wy0 = 1.f - wy1;
  int xx[2] = {x0, x0 + 1}, yy[2] = {y0, y0 + 1};
  float wxs[2] = {wx0, wx1}, wys[2] = {wy0, wy1};
  const short* basep = xt + (size_t)b * 512 * 640 + (size_t)g * 160;
  short* outp = xs + ((size_t)(b * 128 + s)) * 640 + g * 160;
#pragma unroll
  for (int kk = 0; kk < 5; ++kk) {
    int c = kk * 32 + ci;
    float acc = 0.f;
#pragma unroll
    for (int ty = 0; ty < 2; ++ty) {
      int yv = yy[ty];
      bool vy = (yv >= 0) & (yv < 8);
      int yc = min(max(yv, 0), 7);
#pragma unroll
      for (int tx = 0; tx < 2; ++tx) {
        int xv = xx[tx];
        bool vv = vy & (xv >= 0) & (xv < 64);
        int xc = min(max(xv, 0), 63);
        float val = b2f(basep[((size_t)yc * 64 + xc) * 640 + c]);
        acc += wys[ty] * wxs[tx] * (vv ? val : 0.f);
      }
    }
    outp[c] = f2b(acc);
  }
}

// ---------------- generic MFMA GEMM: Out[bz][M][N] = W[M][K] @ X + bias ----------------
// XNK: X stored [bz][N][K]; else [bz][K][N]. W advanced by bz*wStride.
template <bool XNK, bool OUTF32>
__global__ __launch_bounds__(256) void gemm_k(
    const short* __restrict__ W, long long wStride,
    const short* __restrict__ X, const float* __restrict__ bias,
    void* __restrict__ Out, int M, int K, int N)
{
  __shared__ short wa[64 * 64];
  __shared__ short xb[64 * 64];
  const int m0 = blockIdx.x * 64, n0 = blockIdx.y * 64;
  const int bz = blockIdx.z;
  const short* Wp = W + (size_t)bz * wStride;
  const short* Xp = X + (size_t)bz * (size_t)K * N;
  const int tid = threadIdx.x;
  const int lane = tid & 63, wvi = tid >> 6;
  const int wr = wvi >> 1, wc = wvi & 1, lr = lane & 15, lg = lane >> 4;
  f4v acc[2][2];
#pragma unroll
  for (int i = 0; i < 2; ++i)
#pragma unroll
    for (int j = 0; j < 2; ++j) acc[i][j] = (f4v)0.0f;

  const int nk = K >> 5;
  for (int ks = 0; ks < nk; ++ks) {
    __syncthreads();
    {
      int m = tid >> 2, c = tid & 3;
      s8v v = (s8v)(short)0;
      if (m0 + m < M) v = *(const s8v*)&Wp[(size_t)(m0 + m) * K + ks * 32 + c * 8];
      *(s8v*)&wa[m * 64 + ((c ^ (m & 7)) << 3)] = v;
    }
    if (XNK) {
      int n = tid >> 2, c = tid & 3;
      s8v v = *(const s8v*)&Xp[(size_t)(n0 + n) * K + ks * 32 + c * 8];
      *(s8v*)&xb[n * 64 + ((c ^ (n & 7)) << 3)] = v;
    } else {
      int kk = tid >> 3, nn = (tid & 7) * 8;
      s8v v = *(const s8v*)&Xp[(size_t)(ks * 32 + kk) * N + n0 + nn];
#pragma unroll
      for (int j = 0; j < 8; ++j) {
        int n = nn + j;
        xb[n * 64 + (((kk >> 3) ^ (n & 7)) << 3) + (kk & 7)] = v[j];
      }
    }
    __syncthreads();
    s8v av[2], bv[2];
#pragma unroll
    for (int i = 0; i < 2; ++i) {
      int row = wr * 32 + i * 16 + lr;
      av[i] = *(const s8v*)&wa[row * 64 + ((lg ^ (row & 7)) << 3)];
    }
#pragma unroll
    for (int j = 0; j < 2; ++j) {
      int row = wc * 32 + j * 16 + lr;
      bv[j] = *(const s8v*)&xb[row * 64 + ((lg ^ (row & 7)) << 3)];
    }
#pragma unroll
    for (int i = 0; i < 2; ++i)
#pragma unroll
      for (int j = 0; j < 2; ++j)
        acc[i][j] = mfma16(av[i], bv[j], acc[i][j]);
  }

#pragma unroll
  for (int i = 0; i < 2; ++i)
#pragma unroll
    for (int j = 0; j < 2; ++j)
#pragma unroll
      for (int r = 0; r < 4; ++r) {
        int m_g = m0 + wr * 32 + i * 16 + lg * 4 + r;
        int n_g = n0 + wc * 32 + j * 16 + lr;
        if (m_g < M) {
          float val = acc[i][j][r] + (bias ? bias[m_g] : 0.f);
          size_t oidx = (size_t)bz * M * N + (size_t)m_g * N + n_g;
          if (OUTF32) ((float*)Out)[oidx] = val;
          else        ((short*)Out)[oidx] = f2b(val);
        }
      }
}

// ---------------- QK^T + RPE bias + softmax -> p (bf16) ----------------
__global__ __launch_bounds__(256) void qk_softmax_k(
    const short* __restrict__ qg_, const short* __restrict__ kg_,
    const float* __restrict__ pos, const float* __restrict__ rpe,
    short* __restrict__ p)
{
  __shared__ short qT[64 * 128];
  __shared__ short kT[128 * 128];
  __shared__ float rpeL[15 * 127];
  __shared__ float posL[256];
  __shared__ float redA[2][64];
  __shared__ float redB[2][64];
  const int mt = blockIdx.x, bh = blockIdx.y;
  const int b = bh >> 3, h = bh & 7, g = h >> 1;
  const int bg = b * 4 + g;
  const int m0 = mt * 64;
  const int tid = threadIdx.x;

  for (int i = tid; i < 15 * 127; i += 256) rpeL[i] = rpe[(size_t)h * (15 * 127) + i];
  posL[tid] = pos[(size_t)bg * 256 + tid];

  const short* qb_ = qg_ + ((size_t)b * 640 + h * 80) * 512 + m0;
  for (int task = tid; task < 768; task += 256) {
    int hc = task >> 3, mc = task & 7;
    s8v v = (s8v)(short)0;
    if (hc < 80) v = *(const s8v*)&qb_[(size_t)hc * 512 + mc * 8];
#pragma unroll
    for (int j = 0; j < 8; ++j) {
      int m = mc * 8 + j;
      qT[m * 128 + (((hc >> 3) ^ (m & 7)) << 3) + (hc & 7)] = v[j];
    }
  }
  const short* kb_ = kg_ + ((size_t)b * 640 + h * 80) * 128;
  for (int task = tid; task < 1536; task += 256) {
    int hc = task >> 4, nc = task & 15;
    s8v v = (s8v)(short)0;
    if (hc < 80) v = *(const s8v*)&kb_[(size_t)hc * 128 + nc * 8];
#pragma unroll
    for (int j = 0; j < 8; ++j) {
      int n = nc * 8 + j;
      kT[n * 128 + (((hc >> 3) ^ (n & 7)) << 3) + (hc & 7)] = v[j];
    }
  }
  __syncthreads();

  const int lane = tid & 63, wvi = tid >> 6;
  const int wr = wvi >> 1, wc = wvi & 1, lr = lane & 15, lg = lane >> 4;
  f4v acc[2][4];
#pragma unroll
  for (int i = 0; i < 2; ++i)
#pragma unroll
    for (int j = 0; j < 4; ++j) acc[i][j] = (f4v)0.0f;

#pragma unroll
  for (int ks = 0; ks < 3; ++ks) {
    s8v av[2], bv[4];
#pragma unroll
    for (int i = 0; i < 2; ++i) {
      int row = wr * 32 + i * 16 + lr;
      av[i] = *(const s8v*)&qT[row * 128 + (((ks * 4 + lg) ^ (row & 7)) << 3)];
    }
#pragma unroll
    for (int j = 0; j < 4; ++j) {
      int row = wc * 64 + j * 16 + lr;
      bv[j] = *(const s8v*)&kT[row * 128 + (((ks * 4 + lg) ^ (row & 7)) << 3)];
    }
#pragma unroll
    for (int i = 0; i < 2; ++i)
#pragma unroll
      for (int j = 0; j < 4; ++j)
        acc[i][j] = mfma16(av[i], bv[j], acc[i][j]);
  }

  const float scale = 0.11180339887498949f;  // 80^-0.5
  float rmax[2][4];
#pragma unroll
  for (int i = 0; i < 2; ++i)
#pragma unroll
    for (int r = 0; r < 4; ++r) {
      int m_l = wr * 32 + i * 16 + lg * 4 + r;
      int m_g = m0 + m_l;
      float qgy = (float)(m_g >> 6) * 0.25f + (0.125f - 1.f);
      float qgx = (float)(m_g & 63) * 0.03125f + (0.015625f - 1.f);
      float mxv = -1e30f;
#pragma unroll
      for (int j = 0; j < 4; ++j) {
        int n_l = wc * 64 + j * 16 + lr;
        float py = posL[n_l * 2], px = posL[n_l * 2 + 1];
        float dy = (qgy - py) * 0.5f, dx = (qgx - px) * 0.5f;
        float gx = (dx + 1.f) * 63.5f - 0.5f;  // Wi=127
        float gy = (dy + 1.f) * 7.5f - 0.5f;   // Hi=15
        float fx = floorf(gx), fy = floorf(gy);
        int x0 = (int)fx, y0 = (int)fy;
        float wx1 = gx - fx, wx0 = 1.f - wx1;
        float wy1 = gy - fy, wy0 = 1.f - wy1;
        int x1 = x0 + 1, y1 = y0 + 1;
        int xc0 = min(max(x0, 0), 126), xc1 = min(max(x1, 0), 126);
        int yc0 = min(max(y0, 0), 14),  yc1 = min(max(y1, 0), 14);
        float t00 = rpeL[yc0 * 127 + xc0];
        float t01 = rpeL[yc0 * 127 + xc1];
        float t10 = rpeL[yc1 * 127 + xc0];
        float t11 = rpeL[yc1 * 127 + xc1];
        t00 = (x0 >= 0 && x0 < 127 && y0 >= 0 && y0 < 15) ? t00 : 0.f;
        t01 = (x1 >= 0 && x1 < 127 && y0 >= 0 && y0 < 15) ? t01 : 0.f;
        t10 = (x0 >= 0 && x0 < 127 && y1 >= 0 && y1 < 15) ? t10 : 0.f;
        t11 = (x1 >= 0 && x1 < 127 && y1 >= 0 && y1 < 15) ? t11 : 0.f;
        float bias = wy0 * (wx0 * t00 + wx1 * t01) + wy1 * (wx0 * t10 + wx1 * t11);
        float sv = acc[i][j][r] * scale + bias;
        acc[i][j][r] = sv;
        mxv = fmaxf(mxv, sv);
      }
#pragma unroll
      for (int o = 8; o; o >>= 1) mxv = fmaxf(mxv, __shfl_xor(mxv, o));
      rmax[i][r] = mxv;
    }
  if (lr == 0) {
#pragma unroll
    for (int i = 0; i < 2; ++i)
#pragma unroll
      for (int r = 0; r < 4; ++r)
        redA[wc][wr * 32 + i * 16 + lg * 4 + r] = rmax[i][r];
  }
  __syncthreads();
  float rsum[2][4];
#pragma unroll
  for (int i = 0; i < 2; ++i)
#pragma unroll
    for (int r = 0; r < 4; ++r) {
      int row = wr * 32 + i * 16 + lg * 4 + r;
      float mfull = fmaxf(redA[0][row], redA[1][row]);
      float sm = 0.f;
#pragma unroll
      for (int j = 0; j < 4; ++j) {
        float e = __expf(acc[i][j][r] - mfull);
        acc[i][j][r] = e;
        sm += e;
      }
#pragma unroll
      for (int o = 8; o; o >>= 1) sm += __shfl_xor(sm, o);
      rsum[i][r] = sm;
    }
  if (lr == 0) {
#pragma unroll
    for (int i = 0; i < 2; ++i)
#pragma unroll
      for (int r = 0; r < 4; ++r)
        redB[wc][wr * 32 + i * 16 + lg * 4 + r] = rsum[i][r];
  }
  __syncthreads();
  short* pp = p + ((size_t)bh * 512 + m0) * 128;
#pragma unroll
  for (int i = 0; i < 2; ++i)
#pragma unroll
    for (int r = 0; r < 4; ++r) {
      int row = wr * 32 + i * 16 + lg * 4 + r;
      float inv = 1.f / (redB[0][row] + redB[1][row]);
#pragma unroll
      for (int j = 0; j < 4; ++j) {
        int n_l = wc * 64 + j * 16 + lr;
        pp[(size_t)row * 128 + n_l] = f2b(acc[i][j][r] * inv);
      }
    }
}

// =============================== launcher ===============================
extern "C" void kernel_launch(void* const* d_in, const int* in_sizes, int n_in,
                              void* d_out, int out_size, void* d_ws, size_t ws_size,
                              hipStream_t stream) {
  (void)in_sizes; (void)n_in; (void)out_size; (void)ws_size;
  const float* x   = (const float*)d_in[0];
  const float* y   = (const float*)d_in[1];
  const float* w1  = (const float*)d_in[2];
  const float* b1  = (const float*)d_in[3];
  const float* lng = (const float*)d_in[4];
  const float* lnb = (const float*)d_in[5];
  const float* w2  = (const float*)d_in[6];
  const float* qw  = (const float*)d_in[7];
  const float* qb  = (const float*)d_in[8];
  const float* kw  = (const float*)d_in[9];
  const float* kb  = (const float*)d_in[10];
  const float* vw  = (const float*)d_in[11];
  const float* vb  = (const float*)d_in[12];
  const float* ow  = (const float*)d_in[13];
  const float* ob  = (const float*)d_in[14];
  const float* rpe = (const float*)d_in[15];
  float* out = (float*)d_out;
  // out: [32][640][8][64] = 10485760 elems; then pos_out [32][4][4][32][2] = 32768; then ref_out 32768
  float* pos_out = out + 10485760;
  float* ref_out = out + 10518528;

  char* base = (char*)d_ws;
  size_t off = 0;
  auto take = [&](size_t bytes) {
    char* pch = base + off;
    off = (off + bytes + 255) & ~(size_t)255;
    return pch;
  };
  float* pos   = (float*)take(131072);        // [128][128][2] f32
  short* y_bf  = (short*)take(20971520);      // [32][640][512] bf16
  short* qw_bf = (short*)take(819200);
  short* kw_bf = (short*)take(819200);
  short* vw_bf = (short*)take(819200);
  short* ow_bf = (short*)take(819200);
  short* xs_bf = (short*)take(5242880);       // [32][128][640] bf16 (N,K layout)
  short* k_bf  = (short*)take(5242880);       // [32][640][128]
  short* v_bf  = (short*)take(5242880);       // [32][640][128]
  char*  regA  = take(20971520);              // x_t (bf16 [32][512][640]) then q_bf
  short* x_t   = (short*)regA;
  short* q_bf  = (short*)regA;                // [32][640][512]
  char*  regB  = take(20971520);              // conv_out (f32) then ao_bf
  float* co    = (float*)regB;                // [128][128][320]
  short* ao_bf = (short*)regB;                // [32][640][512]
  short* p_ws  = (short*)take(33554432);      // [256][512][128] bf16

  // converts
  cvt_k<<<40960, 256, 0, stream>>>(y,  y_bf,  10485760);
  cvt_k<<<1600,  256, 0, stream>>>(qw, qw_bf, 409600);
  cvt_k<<<1600,  256, 0, stream>>>(kw, kw_bf, 409600);
  cvt_k<<<1600,  256, 0, stream>>>(vw, vw_bf, 409600);
  cvt_k<<<1600,  256, 0, stream>>>(ow, ow_bf, 409600);

  // offset network
  conv_off_k<<<dim3(40, 128), 256, 0, stream>>>(x, y, w1, b1, co);
  ln_proj_k<<<dim3(128, 128), 320, 0, stream>>>(co, lng, lnb, w2, pos, pos_out, ref_out);

  // deformable sampling
  transpose_k<<<dim3(20, 16, 32), dim3(32, 8), 0, stream>>>(x, x_t);
  sample_k<<<dim3(16, 128), 256, 0, stream>>>(x_t, pos, xs_bf);

  // q / k / v projections
  gemm_k<false, false><<<dim3(10, 8, 32), 256, 0, stream>>>(qw_bf, 0LL, y_bf,  qb, q_bf, 640, 640, 512);
  gemm_k<true,  false><<<dim3(10, 2, 32), 256, 0, stream>>>(kw_bf, 0LL, xs_bf, kb, k_bf, 640, 640, 128);
  gemm_k<true,  false><<<dim3(10, 2, 32), 256, 0, stream>>>(vw_bf, 0LL, xs_bf, vb, v_bf, 640, 640, 128);

  // attention
  qk_softmax_k<<<dim3(8, 256), 256, 0, stream>>>(q_bf, k_bf, pos, rpe, p_ws);
  gemm_k<true,  false><<<dim3(2, 8, 256), 256, 0, stream>>>(v_bf, (long long)80 * 128, p_ws, nullptr, ao_bf, 80, 128, 512);

  // output projection
  gemm_k<false, true><<<dim3(10, 8, 32), 256, 0, stream>>>(ow_bf, 0LL, ao_bf, ob, out, 640, 640, 512);
}

// Round 3
// 376.779 us; speedup vs baseline: 1.1264x; 1.1264x over previous
//
#include <hip/hip_runtime.h>

#define DI static __device__ __forceinline__

typedef __attribute__((ext_vector_type(8))) short s8v;
typedef __attribute__((ext_vector_type(4))) float f4v;

DI short f2b(float x) {
  unsigned u = __builtin_bit_cast(unsigned, x);
  u = (u + 0x7fffu + ((u >> 16) & 1u)) >> 16;
  return (short)u;
}
DI float b2f(short s) {
  unsigned u = ((unsigned)(unsigned short)s) << 16;
  return __builtin_bit_cast(float, u);
}
DI f4v mfma16(s8v a, s8v b, f4v c) {
  return __builtin_amdgcn_mfma_f32_16x16x32_bf16(a, b, c, 0, 0, 0);
}

// ---------------- f32 -> bf16 convert ----------------
__global__ __launch_bounds__(256) void cvt_k(const float* __restrict__ src,
                                             short* __restrict__ dst, int n) {
  int i = blockIdx.x * 256 + threadIdx.x;
  if (i < n) dst[i] = f2b(src[i]);
}

// ---------------- grouped 9x9 stride-2 conv (offset net part 1) ----------------
// out: co[n=128][s=128][c=320] fp32, bias added
// Block: (cc = 8-channel chunk, n). 4 waves; wave wvi owns oc pair (2wvi, 2wvi+1).
// Lane: wk = lane&31, hk_a = lane>>5; computes positions (hk_a, wk) and (hk_a+2, wk).
// LDS input layout parity-de-interleaved: si[ch][row 0..15][par][40]; padded coord
// pc = col+4 in 0..71 -> [pc&1][pc>>1]; row = actual+4 (rows 0..3, 12..15 are zero pad).
__global__ __launch_bounds__(256) void conv_off_k(
    const float* __restrict__ x, const float* __restrict__ y,
    const float* __restrict__ w1, const float* __restrict__ b1,
    float* __restrict__ co)
{
  __shared__ float si[8][16][80];   // 40 kB
  __shared__ float sw[8][162];      // 5.1 kB
  const int cc = blockIdx.x;        // channel chunk (8 ch)
  const int n  = blockIdx.y;        // b*4+g
  const int b = n >> 2, g = n & 3;
  const int c0 = cc * 8;
  const float* src = (g < 2 ? x : y) + ((size_t)b * 640 + (g & 1) * 320 + c0) * 512;
  const int tid = threadIdx.x;

  for (int i = tid; i < 8 * 16 * 80; i += 256) ((float*)si)[i] = 0.f;
  for (int i = tid; i < 8 * 162; i += 256) ((float*)sw)[i] = w1[(size_t)c0 * 162 + i];
  __syncthreads();
  for (int i = tid; i < 8 * 512; i += 256) {
    int ch = i >> 9, idx = i & 511;
    int r = idx >> 6, c = idx & 63;
    int pc = c + 4;
    si[ch][r + 4][(pc & 1) * 40 + (pc >> 1)] = src[(size_t)ch * 512 + idx];
  }
  __syncthreads();

  const int lane = tid & 63, wvi = tid >> 6;
  const int wk = lane & 31, hk_a = lane >> 5;
  float a00 = 0.f, a01 = 0.f, a10 = 0.f, a11 = 0.f;  // [oc][posA/posB]
#pragma unroll
  for (int ic = 0; ic < 2; ++ic) {
    const float* ib  = &si[2 * wvi + ic][0][0];
    const float* w0p = &sw[2 * wvi][ic * 81];
    const float* w1p = &sw[2 * wvi + 1][ic * 81];
#pragma unroll
    for (int kh = 0; kh < 9; ++kh) {
      const int ra = (hk_a * 2 + kh) * 80;
      const int rb = ra + 320;                 // +4 rows
      float wA[9], wB[9];
#pragma unroll
      for (int kw = 0; kw < 9; ++kw) { wA[kw] = w0p[kh * 9 + kw]; wB[kw] = w1p[kh * 9 + kw]; }
      float ea[5], eb[5], oa[4], ob[4];
#pragma unroll
      for (int t = 0; t < 5; ++t) { ea[t] = ib[ra + wk + t]; eb[t] = ib[rb + wk + t]; }
#pragma unroll
      for (int t = 0; t < 4; ++t) { oa[t] = ib[ra + 40 + wk + t]; ob[t] = ib[rb + 40 + wk + t]; }
#pragma unroll
      for (int kw = 0; kw < 9; ++kw) {
        float va = (kw & 1) ? oa[kw >> 1] : ea[kw >> 1];
        float vb = (kw & 1) ? ob[kw >> 1] : eb[kw >> 1];
        a00 = fmaf(va, wA[kw], a00);
        a01 = fmaf(vb, wA[kw], a01);
        a10 = fmaf(va, wB[kw], a10);
        a11 = fmaf(vb, wB[kw], a11);
      }
    }
  }
  const float bv0 = b1[c0 + 2 * wvi], bv1 = b1[c0 + 2 * wvi + 1];
  const int sA = hk_a * 32 + wk, sB = sA + 64;
  float2 vA = {a00 + bv0, a10 + bv1};
  float2 vB = {a01 + bv0, a11 + bv1};
  *(float2*)&co[((size_t)n * 128 + sA) * 320 + c0 + 2 * wvi] = vA;
  *(float2*)&co[((size_t)n * 128 + sB) * 320 + c0 + 2 * wvi] = vB;
}

// ---------------- LN + GELU + proj + tanh -> pos (offset net part 2) ----------------
__global__ __launch_bounds__(320) void ln_proj_k(
    const float* __restrict__ co, const float* __restrict__ lng,
    const float* __restrict__ lnb, const float* __restrict__ w2,
    float* __restrict__ pos, float* __restrict__ pos_out, float* __restrict__ ref_out)
{
  const int s = blockIdx.x, n = blockIdx.y;
  const int tid = threadIdx.x;
  __shared__ float rA[8], rB[8];
  float v = co[((size_t)n * 128 + s) * 320 + tid];
  float a = v, b2 = v * v;
#pragma unroll
  for (int o = 32; o; o >>= 1) { a += __shfl_xor(a, o); b2 += __shfl_xor(b2, o); }
  int wid = tid >> 6;
  if ((tid & 63) == 0) { rA[wid] = a; rB[wid] = b2; }
  __syncthreads();
  if (tid == 0) {
    float s1 = 0.f, s2 = 0.f;
    for (int i = 0; i < 5; ++i) { s1 += rA[i]; s2 += rB[i]; }
    rA[6] = s1; rB[6] = s2;
  }
  __syncthreads();
  float mu = rA[6] * (1.f / 320.f);
  float var = rB[6] * (1.f / 320.f) - mu * mu;
  float xn = (v - mu) * rsqrtf(var + 1e-5f) * lng[tid] + lnb[tid];
  float ge = 0.5f * xn * (1.f + erff(xn * 0.70710678118654752f));
  float d0 = ge * w2[tid], d1 = ge * w2[320 + tid];
#pragma unroll
  for (int o = 32; o; o >>= 1) { d0 += __shfl_xor(d0, o); d1 += __shfl_xor(d1, o); }
  __syncthreads();
  if ((tid & 63) == 0) { rA[wid] = d0; rB[wid] = d1; }
  __syncthreads();
  if (tid == 0) {
    float D0 = 0.f, D1 = 0.f;
    for (int i = 0; i < 5; ++i) { D0 += rA[i]; D1 += rB[i]; }
    float oy = tanhf(D0) * 0.5f;      // (1/Hk)*ORF = 2/4
    float ox = tanhf(D1) * 0.0625f;   // (1/Wk)*ORF = 2/32
    int hk = s >> 5, wk = s & 31;
    float ry = ((float)hk + 0.5f) * 0.5f - 1.f;
    float rx = ((float)wk + 0.5f) * 0.0625f - 1.f;
    float py = oy + ry, px = ox + rx;
    size_t o2 = ((size_t)n * 128 + s) * 2;
    pos[o2] = py;     pos[o2 + 1] = px;
    pos_out[o2] = py; pos_out[o2 + 1] = px;
    ref_out[o2] = ry; ref_out[o2 + 1] = rx;
  }
}

// ---------------- transpose x [b][c][hw] f32 -> xt [b][hw][c] bf16 ----------------
__global__ __launch_bounds__(256) void transpose_k(const float* __restrict__ x,
                                                   short* __restrict__ xt) {
  __shared__ float tile[32][33];
  const int ct = blockIdx.x, st = blockIdx.y, b = blockIdx.z;
  const int tx = threadIdx.x, ty = threadIdx.y;
  const float* src = x + ((size_t)b * 640 + ct * 32) * 512 + st * 32;
#pragma unroll
  for (int k2 = 0; k2 < 4; ++k2)
    tile[ty + 8 * k2][tx] = src[(size_t)(ty + 8 * k2) * 512 + tx];
  __syncthreads();
  short* dst = xt + ((size_t)b * 512 + st * 32) * 640 + ct * 32;
#pragma unroll
  for (int k2 = 0; k2 < 4; ++k2)
    dst[(size_t)(ty + 8 * k2) * 640 + tx] = f2b(tile[tx][ty + 8 * k2]);
}

// ---------------- bilinear sampler: xs[b][n=128][c=640] bf16 ----------------
__global__ __launch_bounds__(256) void sample_k(const short* __restrict__ xt,
                                                const float* __restrict__ pos,
                                                short* __restrict__ xs) {
  const int sc = blockIdx.x, bg = blockIdx.y;
  const int b = bg >> 2, g = bg & 3;
  const int t = threadIdx.x;
  const int s = sc * 8 + (t >> 5);
  const int ci = t & 31;
  size_t p2 = ((size_t)bg * 128 + s) * 2;
  float py = pos[p2], px = pos[p2 + 1];
  float gx = (px + 1.f) * 32.f - 0.5f;   // Wi=64
  float gy = (py + 1.f) * 4.f - 0.5f;    // Hi=8
  float fx = floorf(gx), fy = floorf(gy);
  int x0 = (int)fx, y0 = (int)fy;
  float wx1 = gx - fx, wx0 = 1.f - wx1;
  float wy1 = gy - fy, wy0 = 1.f - wy1;
  int xx[2] = {x0, x0 + 1}, yy[2] = {y0, y0 + 1};
  float wxs[2] = {wx0, wx1}, wys[2] = {wy0, wy1};
  const short* basep = xt + (size_t)b * 512 * 640 + (size_t)g * 160;
  short* outp = xs + ((size_t)(b * 128 + s)) * 640 + g * 160;
#pragma unroll
  for (int kk = 0; kk < 5; ++kk) {
    int c = kk * 32 + ci;
    float acc = 0.f;
#pragma unroll
    for (int ty = 0; ty < 2; ++ty) {
      int yv = yy[ty];
      bool vy = (yv >= 0) & (yv < 8);
      int yc = min(max(yv, 0), 7);
#pragma unroll
      for (int tx = 0; tx < 2; ++tx) {
        int xv = xx[tx];
        bool vv = vy & (xv >= 0) & (xv < 64);
        int xc = min(max(xv, 0), 63);
        float val = b2f(basep[((size_t)yc * 64 + xc) * 640 + c]);
        acc += wys[ty] * wxs[tx] * (vv ? val : 0.f);
      }
    }
    outp[c] = f2b(acc);
  }
}

// ---------------- generic MFMA GEMM: Out[bz][M][N] = W[M][K] @ X + bias ----------------
// XNK: X stored [bz][N][K]; else [bz][K][N]. W advanced by bz*wStride.
template <bool XNK, bool OUTF32>
__global__ __launch_bounds__(256) void gemm_k(
    const short* __restrict__ W, long long wStride,
    const short* __restrict__ X, const float* __restrict__ bias,
    void* __restrict__ Out, int M, int K, int N)
{
  __shared__ short wa[64 * 64];
  __shared__ short xb[64 * 64];
  const int m0 = blockIdx.x * 64, n0 = blockIdx.y * 64;
  const int bz = blockIdx.z;
  const short* Wp = W + (size_t)bz * wStride;
  const short* Xp = X + (size_t)bz * (size_t)K * N;
  const int tid = threadIdx.x;
  const int lane = tid & 63, wvi = tid >> 6;
  const int wr = wvi >> 1, wc = wvi & 1, lr = lane & 15, lg = lane >> 4;
  f4v acc[2][2];
#pragma unroll
  for (int i = 0; i < 2; ++i)
#pragma unroll
    for (int j = 0; j < 2; ++j) acc[i][j] = (f4v)0.0f;

  const int nk = K >> 5;
  for (int ks = 0; ks < nk; ++ks) {
    __syncthreads();
    {
      int m = tid >> 2, c = tid & 3;
      s8v v = (s8v)(short)0;
      if (m0 + m < M) v = *(const s8v*)&Wp[(size_t)(m0 + m) * K + ks * 32 + c * 8];
      *(s8v*)&wa[m * 64 + ((c ^ (m & 7)) << 3)] = v;
    }
    if (XNK) {
      int n = tid >> 2, c = tid & 3;
      s8v v = *(const s8v*)&Xp[(size_t)(n0 + n) * K + ks * 32 + c * 8];
      *(s8v*)&xb[n * 64 + ((c ^ (n & 7)) << 3)] = v;
    } else {
      int kk = tid >> 3, nn = (tid & 7) * 8;
      s8v v = *(const s8v*)&Xp[(size_t)(ks * 32 + kk) * N + n0 + nn];
#pragma unroll
      for (int j = 0; j < 8; ++j) {
        int n = nn + j;
        xb[n * 64 + (((kk >> 3) ^ (n & 7)) << 3) + (kk & 7)] = v[j];
      }
    }
    __syncthreads();
    s8v av[2], bv[2];
#pragma unroll
    for (int i = 0; i < 2; ++i) {
      int row = wr * 32 + i * 16 + lr;
      av[i] = *(const s8v*)&wa[row * 64 + ((lg ^ (row & 7)) << 3)];
    }
#pragma unroll
    for (int j = 0; j < 2; ++j) {
      int row = wc * 32 + j * 16 + lr;
      bv[j] = *(const s8v*)&xb[row * 64 + ((lg ^ (row & 7)) << 3)];
    }
#pragma unroll
    for (int i = 0; i < 2; ++i)
#pragma unroll
      for (int j = 0; j < 2; ++j)
        acc[i][j] = mfma16(av[i], bv[j], acc[i][j]);
  }

#pragma unroll
  for (int i = 0; i < 2; ++i)
#pragma unroll
    for (int j = 0; j < 2; ++j)
#pragma unroll
      for (int r = 0; r < 4; ++r) {
        int m_g = m0 + wr * 32 + i * 16 + lg * 4 + r;
        int n_g = n0 + wc * 32 + j * 16 + lr;
        if (m_g < M) {
          float val = acc[i][j][r] + (bias ? bias[m_g] : 0.f);
          size_t oidx = (size_t)bz * M * N + (size_t)m_g * N + n_g;
          if (OUTF32) ((float*)Out)[oidx] = val;
          else        ((short*)Out)[oidx] = f2b(val);
        }
      }
}

// ---------------- QK^T + RPE bias + softmax -> p (bf16) ----------------
__global__ __launch_bounds__(256) void qk_softmax_k(
    const short* __restrict__ qg_, const short* __restrict__ kg_,
    const float* __restrict__ pos, const float* __restrict__ rpe,
    short* __restrict__ p)
{
  __shared__ short qT[64 * 128];
  __shared__ short kT[128 * 128];
  __shared__ float rpeL[15 * 127];
  __shared__ float posL[256];
  __shared__ float redA[2][64];
  __shared__ float redB[2][64];
  const int mt = blockIdx.x, bh = blockIdx.y;
  const int b = bh >> 3, h = bh & 7, g = h >> 1;
  const int bg = b * 4 + g;
  const int m0 = mt * 64;
  const int tid = threadIdx.x;

  for (int i = tid; i < 15 * 127; i += 256) rpeL[i] = rpe[(size_t)h * (15 * 127) + i];
  posL[tid] = pos[(size_t)bg * 256 + tid];

  const short* qb_ = qg_ + ((size_t)b * 640 + h * 80) * 512 + m0;
  for (int task = tid; task < 768; task += 256) {
    int hc = task >> 3, mc = task & 7;
    s8v v = (s8v)(short)0;
    if (hc < 80) v = *(const s8v*)&qb_[(size_t)hc * 512 + mc * 8];
#pragma unroll
    for (int j = 0; j < 8; ++j) {
      int m = mc * 8 + j;
      qT[m * 128 + (((hc >> 3) ^ (m & 7)) << 3) + (hc & 7)] = v[j];
    }
  }
  const short* kb_ = kg_ + ((size_t)b * 640 + h * 80) * 128;
  for (int task = tid; task < 1536; task += 256) {
    int hc = task >> 4, nc = task & 15;
    s8v v = (s8v)(short)0;
    if (hc < 80) v = *(const s8v*)&kb_[(size_t)hc * 128 + nc * 8];
#pragma unroll
    for (int j = 0; j < 8; ++j) {
      int n = nc * 8 + j;
      kT[n * 128 + (((hc >> 3) ^ (n & 7)) << 3) + (hc & 7)] = v[j];
    }
  }
  __syncthreads();

  const int lane = tid & 63, wvi = tid >> 6;
  const int wr = wvi >> 1, wc = wvi & 1, lr = lane & 15, lg = lane >> 4;
  f4v acc[2][4];
#pragma unroll
  for (int i = 0; i < 2; ++i)
#pragma unroll
    for (int j = 0; j < 4; ++j) acc[i][j] = (f4v)0.0f;

#pragma unroll
  for (int ks = 0; ks < 3; ++ks) {
    s8v av[2], bv[4];
#pragma unroll
    for (int i = 0; i < 2; ++i) {
      int row = wr * 32 + i * 16 + lr;
      av[i] = *(const s8v*)&qT[row * 128 + (((ks * 4 + lg) ^ (row & 7)) << 3)];
    }
#pragma unroll
    for (int j = 0; j < 4; ++j) {
      int row = wc * 64 + j * 16 + lr;
      bv[j] = *(const s8v*)&kT[row * 128 + (((ks * 4 + lg) ^ (row & 7)) << 3)];
    }
#pragma unroll
    for (int i = 0; i < 2; ++i)
#pragma unroll
      for (int j = 0; j < 4; ++j)
        acc[i][j] = mfma16(av[i], bv[j], acc[i][j]);
  }

  const float scale = 0.11180339887498949f;  // 80^-0.5
  float rmax[2][4];
#pragma unroll
  for (int i = 0; i < 2; ++i)
#pragma unroll
    for (int r = 0; r < 4; ++r) {
      int m_l = wr * 32 + i * 16 + lg * 4 + r;
      int m_g = m0 + m_l;
      float qgy = (float)(m_g >> 6) * 0.25f + (0.125f - 1.f);
      float qgx = (float)(m_g & 63) * 0.03125f + (0.015625f - 1.f);
      float mxv = -1e30f;
#pragma unroll
      for (int j = 0; j < 4; ++j) {
        int n_l = wc * 64 + j * 16 + lr;
        float py = posL[n_l * 2], px = posL[n_l * 2 + 1];
        float dy = (qgy - py) * 0.5f, dx = (qgx - px) * 0.5f;
        float gx = (dx + 1.f) * 63.5f - 0.5f;  // Wi=127
        float gy = (dy + 1.f) * 7.5f - 0.5f;   // Hi=15
        float fx = floorf(gx), fy = floorf(gy);
        int x0 = (int)fx, y0 = (int)fy;
        float wx1 = gx - fx, wx0 = 1.f - wx1;
        float wy1 = gy - fy, wy0 = 1.f - wy1;
        int x1 = x0 + 1, y1 = y0 + 1;
        int xc0 = min(max(x0, 0), 126), xc1 = min(max(x1, 0), 126);
        int yc0 = min(max(y0, 0), 14),  yc1 = min(max(y1, 0), 14);
        float t00 = rpeL[yc0 * 127 + xc0];
        float t01 = rpeL[yc0 * 127 + xc1];
        float t10 = rpeL[yc1 * 127 + xc0];
        float t11 = rpeL[yc1 * 127 + xc1];
        t00 = (x0 >= 0 && x0 < 127 && y0 >= 0 && y0 < 15) ? t00 : 0.f;
        t01 = (x1 >= 0 && x1 < 127 && y0 >= 0 && y0 < 15) ? t01 : 0.f;
        t10 = (x0 >= 0 && x0 < 127 && y1 >= 0 && y1 < 15) ? t10 : 0.f;
        t11 = (x1 >= 0 && x1 < 127 && y1 >= 0 && y1 < 15) ? t11 : 0.f;
        float bias = wy0 * (wx0 * t00 + wx1 * t01) + wy1 * (wx0 * t10 + wx1 * t11);
        float sv = acc[i][j][r] * scale + bias;
        acc[i][j][r] = sv;
        mxv = fmaxf(mxv, sv);
      }
#pragma unroll
      for (int o = 8; o; o >>= 1) mxv = fmaxf(mxv, __shfl_xor(mxv, o));
      rmax[i][r] = mxv;
    }
  if (lr == 0) {
#pragma unroll
    for (int i = 0; i < 2; ++i)
#pragma unroll
      for (int r = 0; r < 4; ++r)
        redA[wc][wr * 32 + i * 16 + lg * 4 + r] = rmax[i][r];
  }
  __syncthreads();
  float rsum[2][4];
#pragma unroll
  for (int i = 0; i < 2; ++i)
#pragma unroll
    for (int r = 0; r < 4; ++r) {
      int row = wr * 32 + i * 16 + lg * 4 + r;
      float mfull = fmaxf(redA[0][row], redA[1][row]);
      float sm = 0.f;
#pragma unroll
      for (int j = 0; j < 4; ++j) {
        float e = __expf(acc[i][j][r] - mfull);
        acc[i][j][r] = e;
        sm += e;
      }
#pragma unroll
      for (int o = 8; o; o >>= 1) sm += __shfl_xor(sm, o);
      rsum[i][r] = sm;
    }
  if (lr == 0) {
#pragma unroll
    for (int i = 0; i < 2; ++i)
#pragma unroll
      for (int r = 0; r < 4; ++r)
        redB[wc][wr * 32 + i * 16 + lg * 4 + r] = rsum[i][r];
  }
  __syncthreads();
  short* pp = p + ((size_t)bh * 512 + m0) * 128;
#pragma unroll
  for (int i = 0; i < 2; ++i)
#pragma unroll
    for (int r = 0; r < 4; ++r) {
      int row = wr * 32 + i * 16 + lg * 4 + r;
      float inv = 1.f / (redB[0][row] + redB[1][row]);
#pragma unroll
      for (int j = 0; j < 4; ++j) {
        int n_l = wc * 64 + j * 16 + lr;
        pp[(size_t)row * 128 + n_l] = f2b(acc[i][j][r] * inv);
      }
    }
}

// =============================== launcher ===============================
extern "C" void kernel_launch(void* const* d_in, const int* in_sizes, int n_in,
                              void* d_out, int out_size, void* d_ws, size_t ws_size,
                              hipStream_t stream) {
  (void)in_sizes; (void)n_in; (void)out_size; (void)ws_size;
  const float* x   = (const float*)d_in[0];
  const float* y   = (const float*)d_in[1];
  const float* w1  = (const float*)d_in[2];
  const float* b1  = (const float*)d_in[3];
  const float* lng = (const float*)d_in[4];
  const float* lnb = (const float*)d_in[5];
  const float* w2  = (const float*)d_in[6];
  const float* qw  = (const float*)d_in[7];
  const float* qb  = (const float*)d_in[8];
  const float* kw  = (const float*)d_in[9];
  const float* kb  = (const float*)d_in[10];
  const float* vw  = (const float*)d_in[11];
  const float* vb  = (const float*)d_in[12];
  const float* ow  = (const float*)d_in[13];
  const float* ob  = (const float*)d_in[14];
  const float* rpe = (const float*)d_in[15];
  float* out = (float*)d_out;
  // out: [32][640][8][64] = 10485760 elems; then pos_out 32768; then ref_out 32768
  float* pos_out = out + 10485760;
  float* ref_out = out + 10518528;

  char* base = (char*)d_ws;
  size_t off = 0;
  auto take = [&](size_t bytes) {
    char* pch = base + off;
    off = (off + bytes + 255) & ~(size_t)255;
    return pch;
  };
  float* pos   = (float*)take(131072);        // [128][128][2] f32
  short* y_bf  = (short*)take(20971520);      // [32][640][512] bf16
  short* qw_bf = (short*)take(819200);
  short* kw_bf = (short*)take(819200);
  short* vw_bf = (short*)take(819200);
  short* ow_bf = (short*)take(819200);
  short* xs_bf = (short*)take(5242880);       // [32][128][640] bf16 (N,K layout)
  short* k_bf  = (short*)take(5242880);       // [32][640][128]
  short* v_bf  = (short*)take(5242880);       // [32][640][128]
  char*  regA  = take(20971520);              // x_t (bf16 [32][512][640]) then q_bf
  short* x_t   = (short*)regA;
  short* q_bf  = (short*)regA;                // [32][640][512]
  char*  regB  = take(20971520);              // conv_out (f32) then ao_bf
  float* co    = (float*)regB;                // [128][128][320]
  short* ao_bf = (short*)regB;                // [32][640][512]
  short* p_ws  = (short*)take(33554432);      // [256][512][128] bf16

  // converts
  cvt_k<<<40960, 256, 0, stream>>>(y,  y_bf,  10485760);
  cvt_k<<<1600,  256, 0, stream>>>(qw, qw_bf, 409600);
  cvt_k<<<1600,  256, 0, stream>>>(kw, kw_bf, 409600);
  cvt_k<<<1600,  256, 0, stream>>>(vw, vw_bf, 409600);
  cvt_k<<<1600,  256, 0, stream>>>(ow, ow_bf, 409600);

  // offset network
  conv_off_k<<<dim3(40, 128), 256, 0, stream>>>(x, y, w1, b1, co);
  ln_proj_k<<<dim3(128, 128), 320, 0, stream>>>(co, lng, lnb, w2, pos, pos_out, ref_out);

  // deformable sampling
  transpose_k<<<dim3(20, 16, 32), dim3(32, 8), 0, stream>>>(x, x_t);
  sample_k<<<dim3(16, 128), 256, 0, stream>>>(x_t, pos, xs_bf);

  // q / k / v projections
  gemm_k<false, false><<<dim3(10, 8, 32), 256, 0, stream>>>(qw_bf, 0LL, y_bf,  qb, q_bf, 640, 640, 512);
  gemm_k<true,  false><<<dim3(10, 2, 32), 256, 0, stream>>>(kw_bf, 0LL, xs_bf, kb, k_bf, 640, 640, 128);
  gemm_k<true,  false><<<dim3(10, 2, 32), 256, 0, stream>>>(vw_bf, 0LL, xs_bf, vb, v_bf, 640, 640, 128);

  // attention
  qk_softmax_k<<<dim3(8, 256), 256, 0, stream>>>(q_bf, k_bf, pos, rpe, p_ws);
  gemm_k<true,  false><<<dim3(2, 8, 256), 256, 0, stream>>>(v_bf, (long long)80 * 128, p_ws, nullptr, ao_bf, 80, 128, 512);

  // output projection
  gemm_k<false, true><<<dim3(10, 8, 32), 256, 0, stream>>>(ow_bf, 0LL, ao_bf, ob, out, 640, 640, 512);
}

// Round 4
// 343.329 us; speedup vs baseline: 1.2362x; 1.0974x over previous
//
#include <hip/hip_runtime.h>

#define DI static __device__ __forceinline__

typedef __attribute__((ext_vector_type(8))) short s8v;
typedef __attribute__((ext_vector_type(4))) float f4v;

DI short f2b(float x) {
  unsigned u = __builtin_bit_cast(unsigned, x);
  u = (u + 0x7fffu + ((u >> 16) & 1u)) >> 16;
  return (short)u;
}
DI float b2f(short s) {
  unsigned u = ((unsigned)(unsigned short)s) << 16;
  return __builtin_bit_cast(float, u);
}
DI f4v mfma16(s8v a, s8v b, f4v c) {
  return __builtin_amdgcn_mfma_f32_16x16x32_bf16(a, b, c, 0, 0, 0);
}

// ---------------- f32 -> bf16 convert ----------------
__global__ __launch_bounds__(256) void cvt_k(const float* __restrict__ src,
                                             short* __restrict__ dst, int n) {
  int i = blockIdx.x * 256 + threadIdx.x;
  if (i < n) dst[i] = f2b(src[i]);
}

// ---------------- grouped 9x9 stride-2 conv (offset net part 1) ----------------
// out: co[n=128][s=128][c=320] fp32, bias added.
// Block (cc, n). 4 waves; wave wvi owns oc pair (c0+2wvi, +1) = group 2wvi (local ic 2wvi, 2wvi+1).
// Lane: cl = lane&15 -> output cols 2cl, 2cl+1; rg = lane>>4 -> output row rg.
// Weights read via SGPR base (scalar loads) - no LDS, no VALU cost.
// LDS input parity layout: si[ch][padded_row 0..15][par*42 + (pc>>1)], pc = col+4.
__global__ __launch_bounds__(256) void conv_off_k(
    const float* __restrict__ x, const float* __restrict__ y,
    const float* __restrict__ w1, const float* __restrict__ b1,
    float* __restrict__ co)
{
  __shared__ float si[8][16][84];   // 43 kB
  const int cc = blockIdx.x;        // channel chunk (8 ch)
  const int n  = blockIdx.y;        // b*4+g
  const int b = n >> 2, g = n & 3;
  const int c0 = cc * 8;
  const float* src = (g < 2 ? x : y) + ((size_t)b * 640 + (g & 1) * 320 + c0) * 512;
  const int tid = threadIdx.x;

  for (int i = tid; i < 8 * 16 * 84; i += 256) ((float*)si)[i] = 0.f;
  __syncthreads();
  for (int i = tid; i < 8 * 512; i += 256) {
    int ch = i >> 9, idx = i & 511;
    int r = idx >> 6, c = idx & 63;
    int pc = c + 4;
    si[ch][r + 4][(pc & 1) * 42 + (pc >> 1)] = src[(size_t)ch * 512 + idx];
  }
  __syncthreads();

  const int lane = tid & 63, wvi = tid >> 6;
  const int cl = lane & 15, rg = lane >> 4;
  const int ocs = __builtin_amdgcn_readfirstlane(c0 + 2 * wvi);
  const float* wbase = w1 + (size_t)ocs * 162;
  float a00 = 0.f, a01 = 0.f, a10 = 0.f, a11 = 0.f;  // [oc][col0/col1]
#pragma unroll
  for (int ic = 0; ic < 2; ++ic) {
    const float* ib = &si[2 * wvi + ic][0][0];
#pragma unroll
    for (int kh = 0; kh < 9; ++kh) {
      const int rb = (2 * rg + kh) * 84;
      float ev[6], ov[5];
#pragma unroll
      for (int t = 0; t < 6; ++t) ev[t] = ib[rb + 2 * cl + t];
#pragma unroll
      for (int t = 0; t < 5; ++t) ov[t] = ib[rb + 42 + 2 * cl + t];
      const float* wv0 = wbase + ic * 81 + kh * 9;
      const float* wv1 = wv0 + 162;
#pragma unroll
      for (int kw = 0; kw < 9; ++kw) {
        float w0 = wv0[kw], w1v = wv1[kw];
        int j = kw >> 1;
        float v0 = (kw & 1) ? ov[j] : ev[j];           // output col 2cl
        float v1 = (kw & 1) ? ov[j + 1] : ev[j + 1];   // output col 2cl+1
        a00 = fmaf(v0, w0, a00);
        a01 = fmaf(v1, w0, a01);
        a10 = fmaf(v0, w1v, a10);
        a11 = fmaf(v1, w1v, a11);
      }
    }
  }
  const float bv0 = b1[ocs], bv1 = b1[ocs + 1];
  const int s0 = rg * 32 + 2 * cl;
  float2 vA = {a00 + bv0, a10 + bv1};
  float2 vB = {a01 + bv0, a11 + bv1};
  *(float2*)&co[((size_t)n * 128 + s0) * 320 + ocs] = vA;
  *(float2*)&co[((size_t)n * 128 + s0 + 1) * 320 + ocs] = vB;
}

// ---------------- LN + GELU + proj + tanh -> pos (offset net part 2) ----------------
// One wave per position: 5 channels/lane, pure shfl reductions, no LDS.
__global__ __launch_bounds__(256) void ln_proj_k(
    const float* __restrict__ co, const float* __restrict__ lng,
    const float* __restrict__ lnb, const float* __restrict__ w2,
    float* __restrict__ pos, float* __restrict__ pos_out, float* __restrict__ ref_out)
{
  const int n = blockIdx.y;
  const int wvi = threadIdx.x >> 6, lane = threadIdx.x & 63;
  const int s = blockIdx.x * 4 + wvi;
  const float* cp = co + ((size_t)n * 128 + s) * 320;
  float v[5], gw[5], gb[5], p0[5], p1[5];
#pragma unroll
  for (int t = 0; t < 5; ++t) {
    int ch = lane + 64 * t;
    v[t] = cp[ch]; gw[t] = lng[ch]; gb[t] = lnb[ch];
    p0[t] = w2[ch]; p1[t] = w2[320 + ch];
  }
  float s1 = 0.f, s2 = 0.f;
#pragma unroll
  for (int t = 0; t < 5; ++t) { s1 += v[t]; s2 += v[t] * v[t]; }
#pragma unroll
  for (int o = 32; o; o >>= 1) { s1 += __shfl_xor(s1, o); s2 += __shfl_xor(s2, o); }
  float mu = s1 * (1.f / 320.f);
  float var = s2 * (1.f / 320.f) - mu * mu;
  float rstd = rsqrtf(var + 1e-5f);
  float d0 = 0.f, d1 = 0.f;
#pragma unroll
  for (int t = 0; t < 5; ++t) {
    float xn = (v[t] - mu) * rstd * gw[t] + gb[t];
    float ge = 0.5f * xn * (1.f + erff(xn * 0.70710678118654752f));
    d0 = fmaf(ge, p0[t], d0);
    d1 = fmaf(ge, p1[t], d1);
  }
#pragma unroll
  for (int o = 32; o; o >>= 1) { d0 += __shfl_xor(d0, o); d1 += __shfl_xor(d1, o); }
  if (lane == 0) {
    float oy = tanhf(d0) * 0.5f;      // (1/Hk)*ORF = 2/4
    float ox = tanhf(d1) * 0.0625f;   // (1/Wk)*ORF = 2/32
    int hk = s >> 5, wk = s & 31;
    float ry = ((float)hk + 0.5f) * 0.5f - 1.f;
    float rx = ((float)wk + 0.5f) * 0.0625f - 1.f;
    float py = oy + ry, px = ox + rx;
    size_t o2 = ((size_t)n * 128 + s) * 2;
    pos[o2] = py;     pos[o2 + 1] = px;
    pos_out[o2] = py; pos_out[o2 + 1] = px;
    ref_out[o2] = ry; ref_out[o2 + 1] = rx;
  }
}

// ---------------- transpose x [b][c][hw] f32 -> xt [b][hw][c] bf16 ----------------
__global__ __launch_bounds__(256) void transpose_k(const float* __restrict__ x,
                                                   short* __restrict__ xt) {
  __shared__ float tile[32][33];
  const int ct = blockIdx.x, st = blockIdx.y, b = blockIdx.z;
  const int tx = threadIdx.x, ty = threadIdx.y;
  const float* src = x + ((size_t)b * 640 + ct * 32) * 512 + st * 32;
#pragma unroll
  for (int k2 = 0; k2 < 4; ++k2)
    tile[ty + 8 * k2][tx] = src[(size_t)(ty + 8 * k2) * 512 + tx];
  __syncthreads();
  short* dst = xt + ((size_t)b * 512 + st * 32) * 640 + ct * 32;
#pragma unroll
  for (int k2 = 0; k2 < 4; ++k2)
    dst[(size_t)(ty + 8 * k2) * 640 + tx] = f2b(tile[tx][ty + 8 * k2]);
}

// ---------------- bilinear sampler: xs[b][n=128][c=640] bf16 ----------------
__global__ __launch_bounds__(256) void sample_k(const short* __restrict__ xt,
                                                const float* __restrict__ pos,
                                                short* __restrict__ xs) {
  const int sc = blockIdx.x, bg = blockIdx.y;
  const int b = bg >> 2, g = bg & 3;
  const int t = threadIdx.x;
  const int s = sc * 8 + (t >> 5);
  const int ci = t & 31;
  size_t p2 = ((size_t)bg * 128 + s) * 2;
  float py = pos[p2], px = pos[p2 + 1];
  float gx = (px + 1.f) * 32.f - 0.5f;   // Wi=64
  float gy = (py + 1.f) * 4.f - 0.5f;    // Hi=8
  float fx = floorf(gx), fy = floorf(gy);
  int x0 = (int)fx, y0 = (int)fy;
  float wx1 = gx - fx, wx0 = 1.f - wx1;
  float wy1 = gy - fy, wy0 = 1.f - wy1;
  int xx[2] = {x0, x0 + 1}, yy[2] = {y0, y0 + 1};
  float wxs[2] = {wx0, wx1}, wys[2] = {wy0, wy1};
  const short* basep = xt + (size_t)b * 512 * 640 + (size_t)g * 160;
  short* outp = xs + ((size_t)(b * 128 + s)) * 640 + g * 160;
#pragma unroll
  for (int kk = 0; kk < 5; ++kk) {
    int c = kk * 32 + ci;
    float acc = 0.f;
#pragma unroll
    for (int ty = 0; ty < 2; ++ty) {
      int yv = yy[ty];
      bool vy = (yv >= 0) & (yv < 8);
      int yc = min(max(yv, 0), 7);
#pragma unroll
      for (int tx = 0; tx < 2; ++tx) {
        int xv = xx[tx];
        bool vv = vy & (xv >= 0) & (xv < 64);
        int xc = min(max(xv, 0), 63);
        float val = b2f(basep[((size_t)yc * 64 + xc) * 640 + c]);
        acc += wys[ty] * wxs[tx] * (vv ? val : 0.f);
      }
    }
    outp[c] = f2b(acc);
  }
}

// ---------------- generic MFMA GEMM: Out[bz][M][N] = W[M][K] @ X + bias ----------------
// XNK: X stored [bz][N][K]; else [bz][K][N]. W advanced by bz*wStride.
template <bool XNK, bool OUTF32>
__global__ __launch_bounds__(256) void gemm_k(
    const short* __restrict__ W, long long wStride,
    const short* __restrict__ X, const float* __restrict__ bias,
    void* __restrict__ Out, int M, int K, int N)
{
  __shared__ short wa[64 * 64];
  __shared__ short xb[64 * 64];
  const int m0 = blockIdx.x * 64, n0 = blockIdx.y * 64;
  const int bz = blockIdx.z;
  const short* Wp = W + (size_t)bz * wStride;
  const short* Xp = X + (size_t)bz * (size_t)K * N;
  const int tid = threadIdx.x;
  const int lane = tid & 63, wvi = tid >> 6;
  const int wr = wvi >> 1, wc = wvi & 1, lr = lane & 15, lg = lane >> 4;
  f4v acc[2][2];
#pragma unroll
  for (int i = 0; i < 2; ++i)
#pragma unroll
    for (int j = 0; j < 2; ++j) acc[i][j] = (f4v)0.0f;

  const int nk = K >> 5;
  for (int ks = 0; ks < nk; ++ks) {
    __syncthreads();
    {
      int m = tid >> 2, c = tid & 3;
      s8v v = (s8v)(short)0;
      if (m0 + m < M) v = *(const s8v*)&Wp[(size_t)(m0 + m) * K + ks * 32 + c * 8];
      *(s8v*)&wa[m * 64 + ((c ^ (m & 7)) << 3)] = v;
    }
    if (XNK) {
      int n = tid >> 2, c = tid & 3;
      s8v v = *(const s8v*)&Xp[(size_t)(n0 + n) * K + ks * 32 + c * 8];
      *(s8v*)&xb[n * 64 + ((c ^ (n & 7)) << 3)] = v;
    } else {
      int kk = tid >> 3, nn = (tid & 7) * 8;
      s8v v = *(const s8v*)&Xp[(size_t)(ks * 32 + kk) * N + n0 + nn];
#pragma unroll
      for (int j = 0; j < 8; ++j) {
        int n = nn + j;
        xb[n * 64 + (((kk >> 3) ^ (n & 7)) << 3) + (kk & 7)] = v[j];
      }
    }
    __syncthreads();
    s8v av[2], bv[2];
#pragma unroll
    for (int i = 0; i < 2; ++i) {
      int row = wr * 32 + i * 16 + lr;
      av[i] = *(const s8v*)&wa[row * 64 + ((lg ^ (row & 7)) << 3)];
    }
#pragma unroll
    for (int j = 0; j < 2; ++j) {
      int row = wc * 32 + j * 16 + lr;
      bv[j] = *(const s8v*)&xb[row * 64 + ((lg ^ (row & 7)) << 3)];
    }
#pragma unroll
    for (int i = 0; i < 2; ++i)
#pragma unroll
      for (int j = 0; j < 2; ++j)
        acc[i][j] = mfma16(av[i], bv[j], acc[i][j]);
  }

#pragma unroll
  for (int i = 0; i < 2; ++i)
#pragma unroll
    for (int j = 0; j < 2; ++j)
#pragma unroll
      for (int r = 0; r < 4; ++r) {
        int m_g = m0 + wr * 32 + i * 16 + lg * 4 + r;
        int n_g = n0 + wc * 32 + j * 16 + lr;
        if (m_g < M) {
          float val = acc[i][j][r] + (bias ? bias[m_g] : 0.f);
          size_t oidx = (size_t)bz * M * N + (size_t)m_g * N + n_g;
          if (OUTF32) ((float*)Out)[oidx] = val;
          else        ((short*)Out)[oidx] = f2b(val);
        }
      }
}

// ---------------- QK^T + RPE bias + softmax -> p (bf16) ----------------
__global__ __launch_bounds__(256) void qk_softmax_k(
    const short* __restrict__ qg_, const short* __restrict__ kg_,
    const float* __restrict__ pos, const float* __restrict__ rpe,
    short* __restrict__ p)
{
  __shared__ short qT[64 * 128];
  __shared__ short kT[128 * 128];
  __shared__ float rpeL[15 * 127];
  __shared__ float posL[256];
  __shared__ float redA[2][64];
  __shared__ float redB[2][64];
  const int mt = blockIdx.x, bh = blockIdx.y;
  const int b = bh >> 3, h = bh & 7, g = h >> 1;
  const int bg = b * 4 + g;
  const int m0 = mt * 64;
  const int tid = threadIdx.x;

  for (int i = tid; i < 15 * 127; i += 256) rpeL[i] = rpe[(size_t)h * (15 * 127) + i];
  posL[tid] = pos[(size_t)bg * 256 + tid];

  const short* qb_ = qg_ + ((size_t)b * 640 + h * 80) * 512 + m0;
  for (int task = tid; task < 768; task += 256) {
    int hc = task >> 3, mc = task & 7;
    s8v v = (s8v)(short)0;
    if (hc < 80) v = *(const s8v*)&qb_[(size_t)hc * 512 + mc * 8];
#pragma unroll
    for (int j = 0; j < 8; ++j) {
      int m = mc * 8 + j;
      qT[m * 128 + (((hc >> 3) ^ (m & 7)) << 3) + (hc & 7)] = v[j];
    }
  }
  const short* kb_ = kg_ + ((size_t)b * 640 + h * 80) * 128;
  for (int task = tid; task < 1536; task += 256) {
    int hc = task >> 4, nc = task & 15;
    s8v v = (s8v)(short)0;
    if (hc < 80) v = *(const s8v*)&kb_[(size_t)hc * 128 + nc * 8];
#pragma unroll
    for (int j = 0; j < 8; ++j) {
      int n = nc * 8 + j;
      kT[n * 128 + (((hc >> 3) ^ (n & 7)) << 3) + (hc & 7)] = v[j];
    }
  }
  __syncthreads();

  const int lane = tid & 63, wvi = tid >> 6;
  const int wr = wvi >> 1, wc = wvi & 1, lr = lane & 15, lg = lane >> 4;
  f4v acc[2][4];
#pragma unroll
  for (int i = 0; i < 2; ++i)
#pragma unroll
    for (int j = 0; j < 4; ++j) acc[i][j] = (f4v)0.0f;

#pragma unroll
  for (int ks = 0; ks < 3; ++ks) {
    s8v av[2], bv[4];
#pragma unroll
    for (int i = 0; i < 2; ++i) {
      int row = wr * 32 + i * 16 + lr;
      av[i] = *(const s8v*)&qT[row * 128 + (((ks * 4 + lg) ^ (row & 7)) << 3)];
    }
#pragma unroll
    for (int j = 0; j < 4; ++j) {
      int row = wc * 64 + j * 16 + lr;
      bv[j] = *(const s8v*)&kT[row * 128 + (((ks * 4 + lg) ^ (row & 7)) << 3)];
    }
#pragma unroll
    for (int i = 0; i < 2; ++i)
#pragma unroll
      for (int j = 0; j < 4; ++j)
        acc[i][j] = mfma16(av[i], bv[j], acc[i][j]);
  }

  const float scale = 0.11180339887498949f;  // 80^-0.5
  float rmax[2][4];
#pragma unroll
  for (int i = 0; i < 2; ++i)
#pragma unroll
    for (int r = 0; r < 4; ++r) {
      int m_l = wr * 32 + i * 16 + lg * 4 + r;
      int m_g = m0 + m_l;
      float qgy = (float)(m_g >> 6) * 0.25f + (0.125f - 1.f);
      float qgx = (float)(m_g & 63) * 0.03125f + (0.015625f - 1.f);
      float mxv = -1e30f;
#pragma unroll
      for (int j = 0; j < 4; ++j) {
        int n_l = wc * 64 + j * 16 + lr;
        float py = posL[n_l * 2], px = posL[n_l * 2 + 1];
        float dy = (qgy - py) * 0.5f, dx = (qgx - px) * 0.5f;
        float gx = (dx + 1.f) * 63.5f - 0.5f;  // Wi=127
        float gy = (dy + 1.f) * 7.5f - 0.5f;   // Hi=15
        float fx = floorf(gx), fy = floorf(gy);
        int x0 = (int)fx, y0 = (int)fy;
        float wx1 = gx - fx, wx0 = 1.f - wx1;
        float wy1 = gy - fy, wy0 = 1.f - wy1;
        int x1 = x0 + 1, y1 = y0 + 1;
        int xc0 = min(max(x0, 0), 126), xc1 = min(max(x1, 0), 126);
        int yc0 = min(max(y0, 0), 14),  yc1 = min(max(y1, 0), 14);
        float t00 = rpeL[yc0 * 127 + xc0];
        float t01 = rpeL[yc0 * 127 + xc1];
        float t10 = rpeL[yc1 * 127 + xc0];
        float t11 = rpeL[yc1 * 127 + xc1];
        t00 = (x0 >= 0 && x0 < 127 && y0 >= 0 && y0 < 15) ? t00 : 0.f;
        t01 = (x1 >= 0 && x1 < 127 && y0 >= 0 && y0 < 15) ? t01 : 0.f;
        t10 = (x0 >= 0 && x0 < 127 && y1 >= 0 && y1 < 15) ? t10 : 0.f;
        t11 = (x1 >= 0 && x1 < 127 && y1 >= 0 && y1 < 15) ? t11 : 0.f;
        float bias = wy0 * (wx0 * t00 + wx1 * t01) + wy1 * (wx0 * t10 + wx1 * t11);
        float sv = acc[i][j][r] * scale + bias;
        acc[i][j][r] = sv;
        mxv = fmaxf(mxv, sv);
      }
#pragma unroll
      for (int o = 8; o; o >>= 1) mxv = fmaxf(mxv, __shfl_xor(mxv, o));
      rmax[i][r] = mxv;
    }
  if (lr == 0) {
#pragma unroll
    for (int i = 0; i < 2; ++i)
#pragma unroll
      for (int r = 0; r < 4; ++r)
        redA[wc][wr * 32 + i * 16 + lg * 4 + r] = rmax[i][r];
  }
  __syncthreads();
  float rsum[2][4];
#pragma unroll
  for (int i = 0; i < 2; ++i)
#pragma unroll
    for (int r = 0; r < 4; ++r) {
      int row = wr * 32 + i * 16 + lg * 4 + r;
      float mfull = fmaxf(redA[0][row], redA[1][row]);
      float sm = 0.f;
#pragma unroll
      for (int j = 0; j < 4; ++j) {
        float e = __expf(acc[i][j][r] - mfull);
        acc[i][j][r] = e;
        sm += e;
      }
#pragma unroll
      for (int o = 8; o; o >>= 1) sm += __shfl_xor(sm, o);
      rsum[i][r] = sm;
    }
  if (lr == 0) {
#pragma unroll
    for (int i = 0; i < 2; ++i)
#pragma unroll
      for (int r = 0; r < 4; ++r)
        redB[wc][wr * 32 + i * 16 + lg * 4 + r] = rsum[i][r];
  }
  __syncthreads();
  short* pp = p + ((size_t)bh * 512 + m0) * 128;
#pragma unroll
  for (int i = 0; i < 2; ++i)
#pragma unroll
    for (int r = 0; r < 4; ++r) {
      int row = wr * 32 + i * 16 + lg * 4 + r;
      float inv = 1.f / (redB[0][row] + redB[1][row]);
#pragma unroll
      for (int j = 0; j < 4; ++j) {
        int n_l = wc * 64 + j * 16 + lr;
        pp[(size_t)row * 128 + n_l] = f2b(acc[i][j][r] * inv);
      }
    }
}

// =============================== launcher ===============================
extern "C" void kernel_launch(void* const* d_in, const int* in_sizes, int n_in,
                              void* d_out, int out_size, void* d_ws, size_t ws_size,
                              hipStream_t stream) {
  (void)in_sizes; (void)n_in; (void)out_size; (void)ws_size;
  const float* x   = (const float*)d_in[0];
  const float* y   = (const float*)d_in[1];
  const float* w1  = (const float*)d_in[2];
  const float* b1  = (const float*)d_in[3];
  const float* lng = (const float*)d_in[4];
  const float* lnb = (const float*)d_in[5];
  const float* w2  = (const float*)d_in[6];
  const float* qw  = (const float*)d_in[7];
  const float* qb  = (const float*)d_in[8];
  const float* kw  = (const float*)d_in[9];
  const float* kb  = (const float*)d_in[10];
  const float* vw  = (const float*)d_in[11];
  const float* vb  = (const float*)d_in[12];
  const float* ow  = (const float*)d_in[13];
  const float* ob  = (const float*)d_in[14];
  const float* rpe = (const float*)d_in[15];
  float* out = (float*)d_out;
  // out: [32][640][8][64] = 10485760 elems; then pos_out 32768; then ref_out 32768
  float* pos_out = out + 10485760;
  float* ref_out = out + 10518528;

  char* base = (char*)d_ws;
  size_t off = 0;
  auto take = [&](size_t bytes) {
    char* pch = base + off;
    off = (off + bytes + 255) & ~(size_t)255;
    return pch;
  };
  float* pos   = (float*)take(131072);        // [128][128][2] f32
  short* y_bf  = (short*)take(20971520);      // [32][640][512] bf16
  short* qw_bf = (short*)take(819200);
  short* kw_bf = (short*)take(819200);
  short* vw_bf = (short*)take(819200);
  short* ow_bf = (short*)take(819200);
  short* xs_bf = (short*)take(5242880);       // [32][128][640] bf16 (N,K layout)
  short* k_bf  = (short*)take(5242880);       // [32][640][128]
  short* v_bf  = (short*)take(5242880);       // [32][640][128]
  char*  regA  = take(20971520);              // x_t (bf16 [32][512][640]) then q_bf
  short* x_t   = (short*)regA;
  short* q_bf  = (short*)regA;                // [32][640][512]
  char*  regB  = take(20971520);              // conv_out (f32) then ao_bf
  float* co    = (float*)regB;                // [128][128][320]
  short* ao_bf = (short*)regB;                // [32][640][512]
  short* p_ws  = (short*)take(33554432);      // [256][512][128] bf16

  // converts
  cvt_k<<<40960, 256, 0, stream>>>(y,  y_bf,  10485760);
  cvt_k<<<1600,  256, 0, stream>>>(qw, qw_bf, 409600);
  cvt_k<<<1600,  256, 0, stream>>>(kw, kw_bf, 409600);
  cvt_k<<<1600,  256, 0, stream>>>(vw, vw_bf, 409600);
  cvt_k<<<1600,  256, 0, stream>>>(ow, ow_bf, 409600);

  // offset network
  conv_off_k<<<dim3(40, 128), 256, 0, stream>>>(x, y, w1, b1, co);
  ln_proj_k<<<dim3(32, 128), 256, 0, stream>>>(co, lng, lnb, w2, pos, pos_out, ref_out);

  // deformable sampling
  transpose_k<<<dim3(20, 16, 32), dim3(32, 8), 0, stream>>>(x, x_t);
  sample_k<<<dim3(16, 128), 256, 0, stream>>>(x_t, pos, xs_bf);

  // q / k / v projections
  gemm_k<false, false><<<dim3(10, 8, 32), 256, 0, stream>>>(qw_bf, 0LL, y_bf,  qb, q_bf, 640, 640, 512);
  gemm_k<true,  false><<<dim3(10, 2, 32), 256, 0, stream>>>(kw_bf, 0LL, xs_bf, kb, k_bf, 640, 640, 128);
  gemm_k<true,  false><<<dim3(10, 2, 32), 256, 0, stream>>>(vw_bf, 0LL, xs_bf, vb, v_bf, 640, 640, 128);

  // attention
  qk_softmax_k<<<dim3(8, 256), 256, 0, stream>>>(q_bf, k_bf, pos, rpe, p_ws);
  gemm_k<true,  false><<<dim3(2, 8, 256), 256, 0, stream>>>(v_bf, (long long)80 * 128, p_ws, nullptr, ao_bf, 80, 128, 512);

  // output projection
  gemm_k<false, true><<<dim3(10, 8, 32), 256, 0, stream>>>(ow_bf, 0LL, ao_bf, ob, out, 640, 640, 512);
}

// Round 5
// 292.126 us; speedup vs baseline: 1.4528x; 1.1753x over previous
//
#include <hip/hip_runtime.h>

#define DI static __device__ __forceinline__

typedef __attribute__((ext_vector_type(8))) short s8v;
typedef __attribute__((ext_vector_type(4))) float f4v;

DI short f2b(float x) {
  unsigned u = __builtin_bit_cast(unsigned, x);
  u = (u + 0x7fffu + ((u >> 16) & 1u)) >> 16;
  return (short)u;
}
DI float b2f(short s) {
  unsigned u = ((unsigned)(unsigned short)s) << 16;
  return __builtin_bit_cast(float, u);
}
DI f4v mfma16(s8v a, s8v b, f4v c) {
  return __builtin_amdgcn_mfma_f32_16x16x32_bf16(a, b, c, 0, 0, 0);
}

// ---------------- f32 -> bf16 convert ----------------
__global__ __launch_bounds__(256) void cvt_k(const float* __restrict__ src,
                                             short* __restrict__ dst, int n) {
  int i = blockIdx.x * 256 + threadIdx.x;
  if (i < n) dst[i] = f2b(src[i]);
}

// ---------------- grouped 9x9 stride-2 conv (offset net part 1) ----------------
__global__ __launch_bounds__(256) void conv_off_k(
    const float* __restrict__ x, const float* __restrict__ y,
    const float* __restrict__ w1, const float* __restrict__ b1,
    float* __restrict__ co)
{
  __shared__ float si[8][16][84];   // 43 kB
  const int cc = blockIdx.x;        // channel chunk (8 ch)
  const int n  = blockIdx.y;        // b*4+g
  const int b = n >> 2, g = n & 3;
  const int c0 = cc * 8;
  const float* src = (g < 2 ? x : y) + ((size_t)b * 640 + (g & 1) * 320 + c0) * 512;
  const int tid = threadIdx.x;

  for (int i = tid; i < 8 * 16 * 84; i += 256) ((float*)si)[i] = 0.f;
  __syncthreads();
  for (int i = tid; i < 8 * 512; i += 256) {
    int ch = i >> 9, idx = i & 511;
    int r = idx >> 6, c = idx & 63;
    int pc = c + 4;
    si[ch][r + 4][(pc & 1) * 42 + (pc >> 1)] = src[(size_t)ch * 512 + idx];
  }
  __syncthreads();

  const int lane = tid & 63, wvi = tid >> 6;
  const int cl = lane & 15, rg = lane >> 4;
  const int ocs = __builtin_amdgcn_readfirstlane(c0 + 2 * wvi);
  const float* wbase = w1 + (size_t)ocs * 162;
  float a00 = 0.f, a01 = 0.f, a10 = 0.f, a11 = 0.f;  // [oc][col0/col1]
#pragma unroll
  for (int ic = 0; ic < 2; ++ic) {
    const float* ib = &si[2 * wvi + ic][0][0];
#pragma unroll
    for (int kh = 0; kh < 9; ++kh) {
      const int rb = (2 * rg + kh) * 84;
      float ev[6], ov[5];
#pragma unroll
      for (int t = 0; t < 6; ++t) ev[t] = ib[rb + 2 * cl + t];
#pragma unroll
      for (int t = 0; t < 5; ++t) ov[t] = ib[rb + 42 + 2 * cl + t];
      const float* wv0 = wbase + ic * 81 + kh * 9;
      const float* wv1 = wv0 + 162;
#pragma unroll
      for (int kw = 0; kw < 9; ++kw) {
        float w0 = wv0[kw], w1v = wv1[kw];
        int j = kw >> 1;
        float v0 = (kw & 1) ? ov[j] : ev[j];
        float v1 = (kw & 1) ? ov[j + 1] : ev[j + 1];
        a00 = fmaf(v0, w0, a00);
        a01 = fmaf(v1, w0, a01);
        a10 = fmaf(v0, w1v, a10);
        a11 = fmaf(v1, w1v, a11);
      }
    }
  }
  const float bv0 = b1[ocs], bv1 = b1[ocs + 1];
  const int s0 = rg * 32 + 2 * cl;
  float2 vA = {a00 + bv0, a10 + bv1};
  float2 vB = {a01 + bv0, a11 + bv1};
  *(float2*)&co[((size_t)n * 128 + s0) * 320 + ocs] = vA;
  *(float2*)&co[((size_t)n * 128 + s0 + 1) * 320 + ocs] = vB;
}

// ---------------- LN + GELU + proj + tanh -> pos (offset net part 2) ----------------
__global__ __launch_bounds__(256) void ln_proj_k(
    const float* __restrict__ co, const float* __restrict__ lng,
    const float* __restrict__ lnb, const float* __restrict__ w2,
    float* __restrict__ pos, float* __restrict__ pos_out, float* __restrict__ ref_out)
{
  const int n = blockIdx.y;
  const int wvi = threadIdx.x >> 6, lane = threadIdx.x & 63;
  const int s = blockIdx.x * 4 + wvi;
  const float* cp = co + ((size_t)n * 128 + s) * 320;
  float v[5], gw[5], gb[5], p0[5], p1[5];
#pragma unroll
  for (int t = 0; t < 5; ++t) {
    int ch = lane + 64 * t;
    v[t] = cp[ch]; gw[t] = lng[ch]; gb[t] = lnb[ch];
    p0[t] = w2[ch]; p1[t] = w2[320 + ch];
  }
  float s1 = 0.f, s2 = 0.f;
#pragma unroll
  for (int t = 0; t < 5; ++t) { s1 += v[t]; s2 += v[t] * v[t]; }
#pragma unroll
  for (int o = 32; o; o >>= 1) { s1 += __shfl_xor(s1, o); s2 += __shfl_xor(s2, o); }
  float mu = s1 * (1.f / 320.f);
  float var = s2 * (1.f / 320.f) - mu * mu;
  float rstd = rsqrtf(var + 1e-5f);
  float d0 = 0.f, d1 = 0.f;
#pragma unroll
  for (int t = 0; t < 5; ++t) {
    float xn = (v[t] - mu) * rstd * gw[t] + gb[t];
    float ge = 0.5f * xn * (1.f + erff(xn * 0.70710678118654752f));
    d0 = fmaf(ge, p0[t], d0);
    d1 = fmaf(ge, p1[t], d1);
  }
#pragma unroll
  for (int o = 32; o; o >>= 1) { d0 += __shfl_xor(d0, o); d1 += __shfl_xor(d1, o); }
  if (lane == 0) {
    float oy = tanhf(d0) * 0.5f;
    float ox = tanhf(d1) * 0.0625f;
    int hk = s >> 5, wk = s & 31;
    float ry = ((float)hk + 0.5f) * 0.5f - 1.f;
    float rx = ((float)wk + 0.5f) * 0.0625f - 1.f;
    float py = oy + ry, px = ox + rx;
    size_t o2 = ((size_t)n * 128 + s) * 2;
    pos[o2] = py;     pos[o2 + 1] = px;
    pos_out[o2] = py; pos_out[o2 + 1] = px;
    ref_out[o2] = ry; ref_out[o2 + 1] = rx;
  }
}

// ---------------- transpose [b][c][hw] f32 -> [b][hw][c] bf16 ----------------
__global__ __launch_bounds__(256) void transpose_k(const float* __restrict__ x,
                                                   short* __restrict__ xt) {
  __shared__ float tile[32][33];
  const int ct = blockIdx.x, st = blockIdx.y, b = blockIdx.z;
  const int tx = threadIdx.x, ty = threadIdx.y;
  const float* src = x + ((size_t)b * 640 + ct * 32) * 512 + st * 32;
#pragma unroll
  for (int k2 = 0; k2 < 4; ++k2)
    tile[ty + 8 * k2][tx] = src[(size_t)(ty + 8 * k2) * 512 + tx];
  __syncthreads();
  short* dst = xt + ((size_t)b * 512 + st * 32) * 640 + ct * 32;
#pragma unroll
  for (int k2 = 0; k2 < 4; ++k2)
    dst[(size_t)(ty + 8 * k2) * 640 + tx] = f2b(tile[tx][ty + 8 * k2]);
}

// ---------------- bilinear sampler: xs[b][n=128][c=640] bf16 ----------------
__global__ __launch_bounds__(256) void sample_k(const short* __restrict__ xt,
                                                const float* __restrict__ pos,
                                                short* __restrict__ xs) {
  const int sc = blockIdx.x, bg = blockIdx.y;
  const int b = bg >> 2, g = bg & 3;
  const int t = threadIdx.x;
  const int s = sc * 8 + (t >> 5);
  const int ci = t & 31;
  size_t p2 = ((size_t)bg * 128 + s) * 2;
  float py = pos[p2], px = pos[p2 + 1];
  float gx = (px + 1.f) * 32.f - 0.5f;
  float gy = (py + 1.f) * 4.f - 0.5f;
  float fx = floorf(gx), fy = floorf(gy);
  int x0 = (int)fx, y0 = (int)fy;
  float wx1 = gx - fx, wx0 = 1.f - wx1;
  float wy1 = gy - fy, wy0 = 1.f - wy1;
  int xx[2] = {x0, x0 + 1}, yy[2] = {y0, y0 + 1};
  float wxs[2] = {wx0, wx1}, wys[2] = {wy0, wy1};
  const short* basep = xt + (size_t)b * 512 * 640 + (size_t)g * 160;
  short* outp = xs + ((size_t)(b * 128 + s)) * 640 + g * 160;
#pragma unroll
  for (int kk = 0; kk < 5; ++kk) {
    int c = kk * 32 + ci;
    float acc = 0.f;
#pragma unroll
    for (int ty = 0; ty < 2; ++ty) {
      int yv = yy[ty];
      bool vy = (yv >= 0) & (yv < 8);
      int yc = min(max(yv, 0), 7);
#pragma unroll
      for (int tx = 0; tx < 2; ++tx) {
        int xv = xx[tx];
        bool vv = vy & (xv >= 0) & (xv < 64);
        int xc = min(max(xv, 0), 63);
        float val = b2f(basep[((size_t)yc * 64 + xc) * 640 + c]);
        acc += wys[ty] * wxs[tx] * (vv ? val : 0.f);
      }
    }
    outp[c] = f2b(acc);
  }
}

// ---------------- MFMA GEMM (all operands [row][K]): Out[bz][M][N] = W @ X^T + bias --
// W: [bz][M][K] (stride wStride), X: [bz][N][K] (stride xStride).
template <bool BIASN, bool OUTF32>
__global__ __launch_bounds__(256) void gemm_k(
    const short* __restrict__ W, long long wStride,
    const short* __restrict__ X, long long xStride,
    const float* __restrict__ bias, void* __restrict__ Out,
    int M, int K, int N)
{
  __shared__ short wa[64 * 64];
  __shared__ short xb[64 * 64];
  const int m0 = blockIdx.x * 64, n0 = blockIdx.y * 64;
  const int bz = blockIdx.z;
  const short* Wp = W + (size_t)bz * wStride;
  const short* Xp = X + (size_t)bz * xStride;
  const int tid = threadIdx.x;
  const int lane = tid & 63, wvi = tid >> 6;
  const int wr = wvi >> 1, wc = wvi & 1, lr = lane & 15, lg = lane >> 4;
  f4v acc[2][2];
#pragma unroll
  for (int i = 0; i < 2; ++i)
#pragma unroll
    for (int j = 0; j < 2; ++j) acc[i][j] = (f4v)0.0f;

  const int nk = K >> 5;
  for (int ks = 0; ks < nk; ++ks) {
    __syncthreads();
    {
      int m = tid >> 2, c = tid & 3;
      *(s8v*)&wa[m * 64 + ((c ^ (m & 7)) << 3)] =
          *(const s8v*)&Wp[(size_t)(m0 + m) * K + ks * 32 + c * 8];
      int n = tid >> 2;
      *(s8v*)&xb[n * 64 + ((c ^ (n & 7)) << 3)] =
          *(const s8v*)&Xp[(size_t)(n0 + n) * K + ks * 32 + c * 8];
    }
    __syncthreads();
    s8v av[2], bv[2];
#pragma unroll
    for (int i = 0; i < 2; ++i) {
      int row = wr * 32 + i * 16 + lr;
      av[i] = *(const s8v*)&wa[row * 64 + ((lg ^ (row & 7)) << 3)];
    }
#pragma unroll
    for (int j = 0; j < 2; ++j) {
      int row = wc * 32 + j * 16 + lr;
      bv[j] = *(const s8v*)&xb[row * 64 + ((lg ^ (row & 7)) << 3)];
    }
#pragma unroll
    for (int i = 0; i < 2; ++i)
#pragma unroll
      for (int j = 0; j < 2; ++j)
        acc[i][j] = mfma16(av[i], bv[j], acc[i][j]);
  }

#pragma unroll
  for (int i = 0; i < 2; ++i)
#pragma unroll
    for (int j = 0; j < 2; ++j)
#pragma unroll
      for (int r = 0; r < 4; ++r) {
        int m_g = m0 + wr * 32 + i * 16 + lg * 4 + r;
        int n_g = n0 + wc * 32 + j * 16 + lr;
        float val = acc[i][j][r] + (BIASN ? bias[n_g] : bias[m_g]);
        size_t oidx = (size_t)bz * M * N + (size_t)m_g * N + n_g;
        if (OUTF32) ((float*)Out)[oidx] = val;
        else        ((short*)Out)[oidx] = f2b(val);
      }
}

// ---------------- fused QK^T + RPE bias + softmax + PV -> ao_t (bf16) -------------
// q_t: [b][512][640], k_t: [b][128][640], v: [b][640][128], ao_t: [b][512][640]
__global__ __launch_bounds__(256) void qkpv_k(
    const short* __restrict__ q_t, const short* __restrict__ k_t,
    const short* __restrict__ v_, const float* __restrict__ pos,
    const float* __restrict__ rpe, short* __restrict__ ao_t)
{
  __shared__ short qT[64 * 136];    // aliased as pT after softmax
  __shared__ short kT[128 * 136];
  __shared__ short vT[80 * 136];
  __shared__ float rpeL[15 * 127];
  __shared__ float posL[256];
  __shared__ float redA[2][64];
  __shared__ float redB[2][64];
  const int mt = blockIdx.x, bh = blockIdx.y;
  const int b = bh >> 3, h = bh & 7, g = h >> 1;
  const int bg = b * 4 + g;
  const int m0 = mt * 64;
  const int tid = threadIdx.x;

  for (int i = tid; i < 15 * 127; i += 256) rpeL[i] = rpe[(size_t)h * (15 * 127) + i];
  posL[tid] = pos[(size_t)bg * 256 + tid];

  // stage Q (64 rows x 96 ch, ch 80..95 zeroed), K (128 rows x 96), V (80 rows x 128)
  const short* qp = q_t + ((size_t)b * 512 + m0) * 640 + h * 80;
  for (int task = tid; task < 768; task += 256) {
    int m = task / 12, c = task - m * 12;
    s8v v = (s8v)(short)0;
    if (c < 10) v = *(const s8v*)&qp[(size_t)m * 640 + c * 8];
    *(s8v*)&qT[m * 136 + c * 8] = v;
  }
  const short* kp = k_t + (size_t)b * 128 * 640 + h * 80;
  for (int task = tid; task < 1536; task += 256) {
    int n = task / 12, c = task - n * 12;
    s8v v = (s8v)(short)0;
    if (c < 10) v = *(const s8v*)&kp[(size_t)n * 640 + c * 8];
    *(s8v*)&kT[n * 136 + c * 8] = v;
  }
  const short* vp = v_ + ((size_t)b * 640 + h * 80) * 128;
  for (int task = tid; task < 1280; task += 256) {
    int c = task >> 4, nc = task & 15;
    *(s8v*)&vT[c * 136 + nc * 8] = *(const s8v*)&vp[(size_t)c * 128 + nc * 8];
  }
  __syncthreads();

  const int lane = tid & 63, wvi = tid >> 6;
  const int wr = wvi >> 1, wc = wvi & 1, lr = lane & 15, lg = lane >> 4;
  f4v acc[2][4];
#pragma unroll
  for (int i = 0; i < 2; ++i)
#pragma unroll
    for (int j = 0; j < 4; ++j) acc[i][j] = (f4v)0.0f;

#pragma unroll
  for (int ks = 0; ks < 3; ++ks) {
    s8v av[2], bv[4];
#pragma unroll
    for (int i = 0; i < 2; ++i) {
      int row = wr * 32 + i * 16 + lr;
      av[i] = *(const s8v*)&qT[row * 136 + (ks * 4 + lg) * 8];
    }
#pragma unroll
    for (int j = 0; j < 4; ++j) {
      int row = wc * 64 + j * 16 + lr;
      bv[j] = *(const s8v*)&kT[row * 136 + (ks * 4 + lg) * 8];
    }
#pragma unroll
    for (int i = 0; i < 2; ++i)
#pragma unroll
      for (int j = 0; j < 4; ++j)
        acc[i][j] = mfma16(av[i], bv[j], acc[i][j]);
  }

  const float scale = 0.11180339887498949f;  // 80^-0.5
  float rmax[2][4];
#pragma unroll
  for (int i = 0; i < 2; ++i)
#pragma unroll
    for (int r = 0; r < 4; ++r) {
      int m_l = wr * 32 + i * 16 + lg * 4 + r;
      int m_g = m0 + m_l;
      float qgy = (float)(m_g >> 6) * 0.25f + (0.125f - 1.f);
      float qgx = (float)(m_g & 63) * 0.03125f + (0.015625f - 1.f);
      float mxv = -1e30f;
#pragma unroll
      for (int j = 0; j < 4; ++j) {
        int n_l = wc * 64 + j * 16 + lr;
        float py = posL[n_l * 2], px = posL[n_l * 2 + 1];
        float dy = (qgy - py) * 0.5f, dx = (qgx - px) * 0.5f;
        float gx = (dx + 1.f) * 63.5f - 0.5f;
        float gy = (dy + 1.f) * 7.5f - 0.5f;
        float fx = floorf(gx), fy = floorf(gy);
        int x0 = (int)fx, y0 = (int)fy;
        float wx1 = gx - fx, wx0 = 1.f - wx1;
        float wy1 = gy - fy, wy0 = 1.f - wy1;
        int x1 = x0 + 1, y1 = y0 + 1;
        int xc0 = min(max(x0, 0), 126), xc1 = min(max(x1, 0), 126);
        int yc0 = min(max(y0, 0), 14),  yc1 = min(max(y1, 0), 14);
        float t00 = rpeL[yc0 * 127 + xc0];
        float t01 = rpeL[yc0 * 127 + xc1];
        float t10 = rpeL[yc1 * 127 + xc0];
        float t11 = rpeL[yc1 * 127 + xc1];
        t00 = (x0 >= 0 && x0 < 127 && y0 >= 0 && y0 < 15) ? t00 : 0.f;
        t01 = (x1 >= 0 && x1 < 127 && y0 >= 0 && y0 < 15) ? t01 : 0.f;
        t10 = (x0 >= 0 && x0 < 127 && y1 >= 0 && y1 < 15) ? t10 : 0.f;
        t11 = (x1 >= 0 && x1 < 127 && y1 >= 0 && y1 < 15) ? t11 : 0.f;
        float bias = wy0 * (wx0 * t00 + wx1 * t01) + wy1 * (wx0 * t10 + wx1 * t11);
        float sv = acc[i][j][r] * scale + bias;
        acc[i][j][r] = sv;
        mxv = fmaxf(mxv, sv);
      }
#pragma unroll
      for (int o = 8; o; o >>= 1) mxv = fmaxf(mxv, __shfl_xor(mxv, o));
      rmax[i][r] = mxv;
    }
  if (lr == 0) {
#pragma unroll
    for (int i = 0; i < 2; ++i)
#pragma unroll
      for (int r = 0; r < 4; ++r)
        redA[wc][wr * 32 + i * 16 + lg * 4 + r] = rmax[i][r];
  }
  __syncthreads();
  float rsum[2][4];
#pragma unroll
  for (int i = 0; i < 2; ++i)
#pragma unroll
    for (int r = 0; r < 4; ++r) {
      int row = wr * 32 + i * 16 + lg * 4 + r;
      float mfull = fmaxf(redA[0][row], redA[1][row]);
      float sm = 0.f;
#pragma unroll
      for (int j = 0; j < 4; ++j) {
        float e = __expf(acc[i][j][r] - mfull);
        acc[i][j][r] = e;
        sm += e;
      }
#pragma unroll
      for (int o = 8; o; o >>= 1) sm += __shfl_xor(sm, o);
      rsum[i][r] = sm;
    }
  if (lr == 0) {
#pragma unroll
    for (int i = 0; i < 2; ++i)
#pragma unroll
      for (int r = 0; r < 4; ++r)
        redB[wc][wr * 32 + i * 16 + lg * 4 + r] = rsum[i][r];
  }
  __syncthreads();
  // write normalized P (bf16) into pT (aliases qT; all qT reads completed pre-barrier)
  short* pT = &qT[0];
#pragma unroll
  for (int i = 0; i < 2; ++i)
#pragma unroll
    for (int r = 0; r < 4; ++r) {
      int row = wr * 32 + i * 16 + lg * 4 + r;
      float inv = 1.f / (redB[0][row] + redB[1][row]);
#pragma unroll
      for (int j = 0; j < 4; ++j) {
        int n_l = wc * 64 + j * 16 + lr;
        pT[row * 136 + n_l] = f2b(acc[i][j][r] * inv);
      }
    }
  __syncthreads();

  // PV: per wave 16 m-rows x 80 c, K=128
  f4v pacc[5];
#pragma unroll
  for (int t = 0; t < 5; ++t) pacc[t] = (f4v)0.0f;
#pragma unroll
  for (int ks = 0; ks < 4; ++ks) {
    s8v pa = *(const s8v*)&pT[(wvi * 16 + lr) * 136 + ks * 32 + lg * 8];
#pragma unroll
    for (int ct = 0; ct < 5; ++ct) {
      s8v vb = *(const s8v*)&vT[(ct * 16 + lr) * 136 + ks * 32 + lg * 8];
      pacc[ct] = mfma16(pa, vb, pacc[ct]);
    }
  }
  short* aop = ao_t + ((size_t)b * 512 + m0 + wvi * 16) * 640 + h * 80;
#pragma unroll
  for (int ct = 0; ct < 5; ++ct)
#pragma unroll
    for (int r = 0; r < 4; ++r)
      aop[(size_t)(lg * 4 + r) * 640 + ct * 16 + lr] = f2b(pacc[ct][r]);
}

// =============================== launcher ===============================
extern "C" void kernel_launch(void* const* d_in, const int* in_sizes, int n_in,
                              void* d_out, int out_size, void* d_ws, size_t ws_size,
                              hipStream_t stream) {
  (void)in_sizes; (void)n_in; (void)out_size; (void)ws_size;
  const float* x   = (const float*)d_in[0];
  const float* y   = (const float*)d_in[1];
  const float* w1  = (const float*)d_in[2];
  const float* b1  = (const float*)d_in[3];
  const float* lng = (const float*)d_in[4];
  const float* lnb = (const float*)d_in[5];
  const float* w2  = (const float*)d_in[6];
  const float* qw  = (const float*)d_in[7];
  const float* qb  = (const float*)d_in[8];
  const float* kw  = (const float*)d_in[9];
  const float* kb  = (const float*)d_in[10];
  const float* vw  = (const float*)d_in[11];
  const float* vb  = (const float*)d_in[12];
  const float* ow  = (const float*)d_in[13];
  const float* ob  = (const float*)d_in[14];
  const float* rpe = (const float*)d_in[15];
  float* out = (float*)d_out;
  float* pos_out = out + 10485760;
  float* ref_out = out + 10518528;

  char* base = (char*)d_ws;
  size_t off = 0;
  auto take = [&](size_t bytes) {
    char* pch = base + off;
    off = (off + bytes + 255) & ~(size_t)255;
    return pch;
  };
  float* pos   = (float*)take(131072);        // [128][128][2] f32
  short* x_t   = (short*)take(20971520);      // [32][512][640] bf16
  short* y_t   = (short*)take(20971520);      // [32][512][640] bf16
  short* q_t   = (short*)take(20971520);      // [32][512][640] bf16
  short* qw_bf = (short*)take(819200);
  short* kw_bf = (short*)take(819200);
  short* vw_bf = (short*)take(819200);
  short* ow_bf = (short*)take(819200);
  short* xs_bf = (short*)take(5242880);       // [32][128][640] bf16
  short* k_t   = (short*)take(5242880);       // [32][128][640] bf16
  short* v_bf  = (short*)take(5242880);       // [32][640][128] bf16
  char*  regB  = take(20971520);              // co (f32 [128][128][320]) then ao_t
  float* co    = (float*)regB;
  short* ao_t  = (short*)regB;                // [32][512][640] bf16

  // transposes + weight converts
  transpose_k<<<dim3(20, 16, 32), dim3(32, 8), 0, stream>>>(x, x_t);
  transpose_k<<<dim3(20, 16, 32), dim3(32, 8), 0, stream>>>(y, y_t);
  cvt_k<<<1600, 256, 0, stream>>>(qw, qw_bf, 409600);
  cvt_k<<<1600, 256, 0, stream>>>(kw, kw_bf, 409600);
  cvt_k<<<1600, 256, 0, stream>>>(vw, vw_bf, 409600);
  cvt_k<<<1600, 256, 0, stream>>>(ow, ow_bf, 409600);

  // offset network
  conv_off_k<<<dim3(40, 128), 256, 0, stream>>>(x, y, w1, b1, co);
  ln_proj_k<<<dim3(32, 128), 256, 0, stream>>>(co, lng, lnb, w2, pos, pos_out, ref_out);

  // deformable sampling
  sample_k<<<dim3(16, 128), 256, 0, stream>>>(x_t, pos, xs_bf);

  // projections (all [row][K] GEMMs)
  gemm_k<true,  false><<<dim3(8, 10, 32), 256, 0, stream>>>(y_t, 512LL * 640, qw_bf, 0LL, qb, q_t, 512, 640, 640);
  gemm_k<true,  false><<<dim3(2, 10, 32), 256, 0, stream>>>(xs_bf, 128LL * 640, kw_bf, 0LL, kb, k_t, 128, 640, 640);
  gemm_k<false, false><<<dim3(10, 2, 32), 256, 0, stream>>>(vw_bf, 0LL, xs_bf, 128LL * 640, vb, v_bf, 640, 640, 128);

  // fused attention (QK^T + bias + softmax + PV)
  qkpv_k<<<dim3(8, 256), 256, 0, stream>>>(q_t, k_t, v_bf, pos, rpe, ao_t);

  // output projection (f32 out)
  gemm_k<false, true><<<dim3(10, 8, 32), 256, 0, stream>>>(ow_bf, 0LL, ao_t, 512LL * 640, ob, out, 640, 640, 512);
}

// Round 6
// 250.300 us; speedup vs baseline: 1.6956x; 1.1671x over previous
//
#include <hip/hip_runtime.h>

#define DI static __device__ __forceinline__

typedef __attribute__((ext_vector_type(8))) short s8v;
typedef __attribute__((ext_vector_type(4))) float f4v;

DI short f2b(float x) {
  unsigned u = __builtin_bit_cast(unsigned, x);
  u = (u + 0x7fffu + ((u >> 16) & 1u)) >> 16;
  return (short)u;
}
DI float b2f(short s) {
  unsigned u = ((unsigned)(unsigned short)s) << 16;
  return __builtin_bit_cast(float, u);
}
DI f4v mfma16(s8v a, s8v b, f4v c) {
  return __builtin_amdgcn_mfma_f32_16x16x32_bf16(a, b, c, 0, 0, 0);
}

// ---------------- f32 -> bf16 convert ----------------
__global__ __launch_bounds__(256) void cvt_k(const float* __restrict__ src,
                                             short* __restrict__ dst, int n) {
  int i = blockIdx.x * 256 + threadIdx.x;
  if (i < n) dst[i] = f2b(src[i]);
}

// ---------------- grouped 9x9 stride-2 conv (offset net part 1) ----------------
__global__ __launch_bounds__(256) void conv_off_k(
    const float* __restrict__ x, const float* __restrict__ y,
    const float* __restrict__ w1, const float* __restrict__ b1,
    float* __restrict__ co)
{
  __shared__ float si[8][16][84];   // 43 kB
  const int cc = blockIdx.x;        // channel chunk (8 ch)
  const int n  = blockIdx.y;        // b*4+g
  const int b = n >> 2, g = n & 3;
  const int c0 = cc * 8;
  const float* src = (g < 2 ? x : y) + ((size_t)b * 640 + (g & 1) * 320 + c0) * 512;
  const int tid = threadIdx.x;

  for (int i = tid; i < 8 * 16 * 84; i += 256) ((float*)si)[i] = 0.f;
  __syncthreads();
  for (int i = tid; i < 8 * 512; i += 256) {
    int ch = i >> 9, idx = i & 511;
    int r = idx >> 6, c = idx & 63;
    int pc = c + 4;
    si[ch][r + 4][(pc & 1) * 42 + (pc >> 1)] = src[(size_t)ch * 512 + idx];
  }
  __syncthreads();

  const int lane = tid & 63, wvi = tid >> 6;
  const int cl = lane & 15, rg = lane >> 4;
  const int ocs = __builtin_amdgcn_readfirstlane(c0 + 2 * wvi);
  const float* wbase = w1 + (size_t)ocs * 162;
  float a00 = 0.f, a01 = 0.f, a10 = 0.f, a11 = 0.f;  // [oc][col0/col1]
#pragma unroll
  for (int ic = 0; ic < 2; ++ic) {
    const float* ib = &si[2 * wvi + ic][0][0];
#pragma unroll
    for (int kh = 0; kh < 9; ++kh) {
      const int rb = (2 * rg + kh) * 84;
      float ev[6], ov[5];
#pragma unroll
      for (int t = 0; t < 6; ++t) ev[t] = ib[rb + 2 * cl + t];
#pragma unroll
      for (int t = 0; t < 5; ++t) ov[t] = ib[rb + 42 + 2 * cl + t];
      const float* wv0 = wbase + ic * 81 + kh * 9;
      const float* wv1 = wv0 + 162;
#pragma unroll
      for (int kw = 0; kw < 9; ++kw) {
        float w0 = wv0[kw], w1v = wv1[kw];
        int j = kw >> 1;
        float v0 = (kw & 1) ? ov[j] : ev[j];
        float v1 = (kw & 1) ? ov[j + 1] : ev[j + 1];
        a00 = fmaf(v0, w0, a00);
        a01 = fmaf(v1, w0, a01);
        a10 = fmaf(v0, w1v, a10);
        a11 = fmaf(v1, w1v, a11);
      }
    }
  }
  const float bv0 = b1[ocs], bv1 = b1[ocs + 1];
  const int s0 = rg * 32 + 2 * cl;
  float2 vA = {a00 + bv0, a10 + bv1};
  float2 vB = {a01 + bv0, a11 + bv1};
  *(float2*)&co[((size_t)n * 128 + s0) * 320 + ocs] = vA;
  *(float2*)&co[((size_t)n * 128 + s0 + 1) * 320 + ocs] = vB;
}

// ---------------- LN + GELU + proj + tanh -> pos (offset net part 2) ----------------
__global__ __launch_bounds__(256) void ln_proj_k(
    const float* __restrict__ co, const float* __restrict__ lng,
    const float* __restrict__ lnb, const float* __restrict__ w2,
    float* __restrict__ pos, float* __restrict__ pos_out, float* __restrict__ ref_out)
{
  const int n = blockIdx.y;
  const int wvi = threadIdx.x >> 6, lane = threadIdx.x & 63;
  const int s = blockIdx.x * 4 + wvi;
  const float* cp = co + ((size_t)n * 128 + s) * 320;
  float v[5], gw[5], gb[5], p0[5], p1[5];
#pragma unroll
  for (int t = 0; t < 5; ++t) {
    int ch = lane + 64 * t;
    v[t] = cp[ch]; gw[t] = lng[ch]; gb[t] = lnb[ch];
    p0[t] = w2[ch]; p1[t] = w2[320 + ch];
  }
  float s1 = 0.f, s2 = 0.f;
#pragma unroll
  for (int t = 0; t < 5; ++t) { s1 += v[t]; s2 += v[t] * v[t]; }
#pragma unroll
  for (int o = 32; o; o >>= 1) { s1 += __shfl_xor(s1, o); s2 += __shfl_xor(s2, o); }
  float mu = s1 * (1.f / 320.f);
  float var = s2 * (1.f / 320.f) - mu * mu;
  float rstd = rsqrtf(var + 1e-5f);
  float d0 = 0.f, d1 = 0.f;
#pragma unroll
  for (int t = 0; t < 5; ++t) {
    float xn = (v[t] - mu) * rstd * gw[t] + gb[t];
    float ge = 0.5f * xn * (1.f + erff(xn * 0.70710678118654752f));
    d0 = fmaf(ge, p0[t], d0);
    d1 = fmaf(ge, p1[t], d1);
  }
#pragma unroll
  for (int o = 32; o; o >>= 1) { d0 += __shfl_xor(d0, o); d1 += __shfl_xor(d1, o); }
  if (lane == 0) {
    float oy = tanhf(d0) * 0.5f;
    float ox = tanhf(d1) * 0.0625f;
    int hk = s >> 5, wk = s & 31;
    float ry = ((float)hk + 0.5f) * 0.5f - 1.f;
    float rx = ((float)wk + 0.5f) * 0.0625f - 1.f;
    float py = oy + ry, px = ox + rx;
    size_t o2 = ((size_t)n * 128 + s) * 2;
    pos[o2] = py;     pos[o2 + 1] = px;
    pos_out[o2] = py; pos_out[o2 + 1] = px;
    ref_out[o2] = ry; ref_out[o2 + 1] = rx;
  }
}

// ---------------- transpose [b][c][hw] f32 -> [b][hw][c] bf16 ----------------
__global__ __launch_bounds__(256) void transpose_k(const float* __restrict__ x,
                                                   short* __restrict__ xt) {
  __shared__ float tile[32][33];
  const int ct = blockIdx.x, st = blockIdx.y, b = blockIdx.z;
  const int tx = threadIdx.x, ty = threadIdx.y;
  const float* src = x + ((size_t)b * 640 + ct * 32) * 512 + st * 32;
#pragma unroll
  for (int k2 = 0; k2 < 4; ++k2)
    tile[ty + 8 * k2][tx] = src[(size_t)(ty + 8 * k2) * 512 + tx];
  __syncthreads();
  short* dst = xt + ((size_t)b * 512 + st * 32) * 640 + ct * 32;
#pragma unroll
  for (int k2 = 0; k2 < 4; ++k2)
    dst[(size_t)(ty + 8 * k2) * 640 + tx] = f2b(tile[tx][ty + 8 * k2]);
}

// ---------------- bilinear sampler: xs[b][n=128][c=640] bf16 ----------------
__global__ __launch_bounds__(256) void sample_k(const short* __restrict__ xt,
                                                const float* __restrict__ pos,
                                                short* __restrict__ xs) {
  const int sc = blockIdx.x, bg = blockIdx.y;
  const int b = bg >> 2, g = bg & 3;
  const int t = threadIdx.x;
  const int s = sc * 8 + (t >> 5);
  const int ci = t & 31;
  size_t p2 = ((size_t)bg * 128 + s) * 2;
  float py = pos[p2], px = pos[p2 + 1];
  float gx = (px + 1.f) * 32.f - 0.5f;
  float gy = (py + 1.f) * 4.f - 0.5f;
  float fx = floorf(gx), fy = floorf(gy);
  int x0 = (int)fx, y0 = (int)fy;
  float wx1 = gx - fx, wx0 = 1.f - wx1;
  float wy1 = gy - fy, wy0 = 1.f - wy1;
  int xx[2] = {x0, x0 + 1}, yy[2] = {y0, y0 + 1};
  float wxs[2] = {wx0, wx1}, wys[2] = {wy0, wy1};
  const short* basep = xt + (size_t)b * 512 * 640 + (size_t)g * 160;
  short* outp = xs + ((size_t)(b * 128 + s)) * 640 + g * 160;
#pragma unroll
  for (int kk = 0; kk < 5; ++kk) {
    int c = kk * 32 + ci;
    float acc = 0.f;
#pragma unroll
    for (int ty = 0; ty < 2; ++ty) {
      int yv = yy[ty];
      bool vy = (yv >= 0) & (yv < 8);
      int yc = min(max(yv, 0), 7);
#pragma unroll
      for (int tx = 0; tx < 2; ++tx) {
        int xv = xx[tx];
        bool vv = vy & (xv >= 0) & (xv < 64);
        int xc = min(max(xv, 0), 63);
        float val = b2f(basep[((size_t)yc * 64 + xc) * 640 + c]);
        acc += wys[ty] * wxs[tx] * (vv ? val : 0.f);
      }
    }
    outp[c] = f2b(acc);
  }
}

// ---------------- MFMA GEMM (all operands [row][K]): Out[bz][M][N] = W @ X^T + bias --
// W: [bz][M][K] (stride wStride), X: [bz][N][K] (stride xStride).
template <bool BIASN, bool OUTF32>
__global__ __launch_bounds__(256) void gemm_k(
    const short* __restrict__ W, long long wStride,
    const short* __restrict__ X, long long xStride,
    const float* __restrict__ bias, void* __restrict__ Out,
    int M, int K, int N)
{
  __shared__ short wa[64 * 64];
  __shared__ short xb[64 * 64];
  const int m0 = blockIdx.x * 64, n0 = blockIdx.y * 64;
  const int bz = blockIdx.z;
  const short* Wp = W + (size_t)bz * wStride;
  const short* Xp = X + (size_t)bz * xStride;
  const int tid = threadIdx.x;
  const int lane = tid & 63, wvi = tid >> 6;
  const int wr = wvi >> 1, wc = wvi & 1, lr = lane & 15, lg = lane >> 4;
  f4v acc[2][2];
#pragma unroll
  for (int i = 0; i < 2; ++i)
#pragma unroll
    for (int j = 0; j < 2; ++j) acc[i][j] = (f4v)0.0f;

  const int nk = K >> 5;
  for (int ks = 0; ks < nk; ++ks) {
    __syncthreads();
    {
      int m = tid >> 2, c = tid & 3;
      *(s8v*)&wa[m * 64 + ((c ^ (m & 7)) << 3)] =
          *(const s8v*)&Wp[(size_t)(m0 + m) * K + ks * 32 + c * 8];
      int n = tid >> 2;
      *(s8v*)&xb[n * 64 + ((c ^ (n & 7)) << 3)] =
          *(const s8v*)&Xp[(size_t)(n0 + n) * K + ks * 32 + c * 8];
    }
    __syncthreads();
    s8v av[2], bv[2];
#pragma unroll
    for (int i = 0; i < 2; ++i) {
      int row = wr * 32 + i * 16 + lr;
      av[i] = *(const s8v*)&wa[row * 64 + ((lg ^ (row & 7)) << 3)];
    }
#pragma unroll
    for (int j = 0; j < 2; ++j) {
      int row = wc * 32 + j * 16 + lr;
      bv[j] = *(const s8v*)&xb[row * 64 + ((lg ^ (row & 7)) << 3)];
    }
#pragma unroll
    for (int i = 0; i < 2; ++i)
#pragma unroll
      for (int j = 0; j < 2; ++j)
        acc[i][j] = mfma16(av[i], bv[j], acc[i][j]);
  }

#pragma unroll
  for (int i = 0; i < 2; ++i)
#pragma unroll
    for (int j = 0; j < 2; ++j)
#pragma unroll
      for (int r = 0; r < 4; ++r) {
        int m_g = m0 + wr * 32 + i * 16 + lg * 4 + r;
        int n_g = n0 + wc * 32 + j * 16 + lr;
        float val = acc[i][j][r] + (BIASN ? bias[n_g] : bias[m_g]);
        size_t oidx = (size_t)bz * M * N + (size_t)m_g * N + n_g;
        if (OUTF32) ((float*)Out)[oidx] = val;
        else        ((short*)Out)[oidx] = f2b(val);
      }
}

// ---------------- fused QK^T + RPE bias + softmax + PV -> ao_t (bf16) -------------
// q_t: [b][512][640], k_t: [b][128][640], v: [b][640][128], ao_t: [b][512][640]
// MFMA operands load directly from global (L2-resident); only P + rpe live in LDS.
__global__ __launch_bounds__(256) void qkpv_k(
    const short* __restrict__ q_t, const short* __restrict__ k_t,
    const short* __restrict__ v_, const float* __restrict__ pos,
    const float* __restrict__ rpe, short* __restrict__ ao_t)
{
  __shared__ short pT[64 * 136];
  __shared__ float rpeL[15 * 127];
  __shared__ float posL[256];
  __shared__ float redA[2][64];
  __shared__ float redB[2][64];
  const int mt = blockIdx.x, bh = blockIdx.y;
  const int b = bh >> 3, h = bh & 7, g = h >> 1;
  const int bg = b * 4 + g;
  const int m0 = mt * 64;
  const int tid = threadIdx.x;

  for (int i = tid; i < 15 * 127; i += 256) rpeL[i] = rpe[(size_t)h * (15 * 127) + i];
  posL[tid] = pos[(size_t)bg * 256 + tid];

  const int lane = tid & 63, wvi = tid >> 6;
  const int wr = wvi >> 1, wc = wvi & 1, lr = lane & 15, lg = lane >> 4;

  // ---- QK^T: fragments straight from global ----
  const short* qp = q_t + ((size_t)b * 512 + m0) * 640 + h * 80;
  const short* kp = k_t + (size_t)b * 128 * 640 + h * 80;
  f4v acc[2][4];
#pragma unroll
  for (int i = 0; i < 2; ++i)
#pragma unroll
    for (int j = 0; j < 4; ++j) acc[i][j] = (f4v)0.0f;

#pragma unroll
  for (int ks = 0; ks < 3; ++ks) {
    const int ch = (ks * 4 + lg) * 8;     // 0..88; >=80 invalid
    const bool chv = ch < 80;
    s8v av[2], bv[4];
#pragma unroll
    for (int i = 0; i < 2; ++i) {
      int row = wr * 32 + i * 16 + lr;
      av[i] = chv ? *(const s8v*)&qp[(size_t)row * 640 + ch] : (s8v)(short)0;
    }
#pragma unroll
    for (int j = 0; j < 4; ++j) {
      int row = wc * 64 + j * 16 + lr;
      bv[j] = chv ? *(const s8v*)&kp[(size_t)row * 640 + ch] : (s8v)(short)0;
    }
#pragma unroll
    for (int i = 0; i < 2; ++i)
#pragma unroll
      for (int j = 0; j < 4; ++j)
        acc[i][j] = mfma16(av[i], bv[j], acc[i][j]);
  }
  __syncthreads();   // rpeL/posL ready (overlapped with MFMA above)

  const float scale = 0.11180339887498949f;  // 80^-0.5
  float rmax[2][4];
#pragma unroll
  for (int i = 0; i < 2; ++i)
#pragma unroll
    for (int r = 0; r < 4; ++r) {
      int m_l = wr * 32 + i * 16 + lg * 4 + r;
      int m_g = m0 + m_l;
      float qgy = (float)(m_g >> 6) * 0.25f + (0.125f - 1.f);
      float qgx = (float)(m_g & 63) * 0.03125f + (0.015625f - 1.f);
      float mxv = -1e30f;
#pragma unroll
      for (int j = 0; j < 4; ++j) {
        int n_l = wc * 64 + j * 16 + lr;
        float py = posL[n_l * 2], px = posL[n_l * 2 + 1];
        float dy = (qgy - py) * 0.5f, dx = (qgx - px) * 0.5f;
        float gx = (dx + 1.f) * 63.5f - 0.5f;
        float gy = (dy + 1.f) * 7.5f - 0.5f;
        float fx = floorf(gx), fy = floorf(gy);
        int x0 = (int)fx, y0 = (int)fy;
        float wx1 = gx - fx, wx0 = 1.f - wx1;
        float wy1 = gy - fy, wy0 = 1.f - wy1;
        int x1 = x0 + 1, y1 = y0 + 1;
        int xc0 = min(max(x0, 0), 126), xc1 = min(max(x1, 0), 126);
        int yc0 = min(max(y0, 0), 14),  yc1 = min(max(y1, 0), 14);
        float t00 = rpeL[yc0 * 127 + xc0];
        float t01 = rpeL[yc0 * 127 + xc1];
        float t10 = rpeL[yc1 * 127 + xc0];
        float t11 = rpeL[yc1 * 127 + xc1];
        t00 = (x0 >= 0 && x0 < 127 && y0 >= 0 && y0 < 15) ? t00 : 0.f;
        t01 = (x1 >= 0 && x1 < 127 && y0 >= 0 && y0 < 15) ? t01 : 0.f;
        t10 = (x0 >= 0 && x0 < 127 && y1 >= 0 && y1 < 15) ? t10 : 0.f;
        t11 = (x1 >= 0 && x1 < 127 && y1 >= 0 && y1 < 15) ? t11 : 0.f;
        float bias = wy0 * (wx0 * t00 + wx1 * t01) + wy1 * (wx0 * t10 + wx1 * t11);
        float sv = acc[i][j][r] * scale + bias;
        acc[i][j][r] = sv;
        mxv = fmaxf(mxv, sv);
      }
#pragma unroll
      for (int o = 8; o; o >>= 1) mxv = fmaxf(mxv, __shfl_xor(mxv, o));
      rmax[i][r] = mxv;
    }
  if (lr == 0) {
#pragma unroll
    for (int i = 0; i < 2; ++i)
#pragma unroll
      for (int r = 0; r < 4; ++r)
        redA[wc][wr * 32 + i * 16 + lg * 4 + r] = rmax[i][r];
  }
  __syncthreads();
  float rsum[2][4];
#pragma unroll
  for (int i = 0; i < 2; ++i)
#pragma unroll
    for (int r = 0; r < 4; ++r) {
      int row = wr * 32 + i * 16 + lg * 4 + r;
      float mfull = fmaxf(redA[0][row], redA[1][row]);
      float sm = 0.f;
#pragma unroll
      for (int j = 0; j < 4; ++j) {
        float e = __expf(acc[i][j][r] - mfull);
        acc[i][j][r] = e;
        sm += e;
      }
#pragma unroll
      for (int o = 8; o; o >>= 1) sm += __shfl_xor(sm, o);
      rsum[i][r] = sm;
    }
  if (lr == 0) {
#pragma unroll
    for (int i = 0; i < 2; ++i)
#pragma unroll
      for (int r = 0; r < 4; ++r)
        redB[wc][wr * 32 + i * 16 + lg * 4 + r] = rsum[i][r];
  }
  __syncthreads();
  // write normalized P (bf16) into pT
#pragma unroll
  for (int i = 0; i < 2; ++i)
#pragma unroll
    for (int r = 0; r < 4; ++r) {
      int row = wr * 32 + i * 16 + lg * 4 + r;
      float inv = 1.f / (redB[0][row] + redB[1][row]);
#pragma unroll
      for (int j = 0; j < 4; ++j) {
        int n_l = wc * 64 + j * 16 + lr;
        pT[row * 136 + n_l] = f2b(acc[i][j][r] * inv);
      }
    }
  __syncthreads();

  // ---- PV: P from LDS, V fragments straight from global ----
  const short* vp = v_ + ((size_t)b * 640 + h * 80) * 128;
  f4v pacc[5];
#pragma unroll
  for (int t = 0; t < 5; ++t) pacc[t] = (f4v)0.0f;
#pragma unroll
  for (int ks = 0; ks < 4; ++ks) {
    s8v pa = *(const s8v*)&pT[(wvi * 16 + lr) * 136 + ks * 32 + lg * 8];
#pragma unroll
    for (int ct = 0; ct < 5; ++ct) {
      s8v vb = *(const s8v*)&vp[(size_t)(ct * 16 + lr) * 128 + ks * 32 + lg * 8];
      pacc[ct] = mfma16(pa, vb, pacc[ct]);
    }
  }
  short* aop = ao_t + ((size_t)b * 512 + m0 + wvi * 16) * 640 + h * 80;
#pragma unroll
  for (int ct = 0; ct < 5; ++ct)
#pragma unroll
    for (int r = 0; r < 4; ++r)
      aop[(size_t)(lg * 4 + r) * 640 + ct * 16 + lr] = f2b(pacc[ct][r]);
}

// =============================== launcher ===============================
extern "C" void kernel_launch(void* const* d_in, const int* in_sizes, int n_in,
                              void* d_out, int out_size, void* d_ws, size_t ws_size,
                              hipStream_t stream) {
  (void)in_sizes; (void)n_in; (void)out_size; (void)ws_size;
  const float* x   = (const float*)d_in[0];
  const float* y   = (const float*)d_in[1];
  const float* w1  = (const float*)d_in[2];
  const float* b1  = (const float*)d_in[3];
  const float* lng = (const float*)d_in[4];
  const float* lnb = (const float*)d_in[5];
  const float* w2  = (const float*)d_in[6];
  const float* qw  = (const float*)d_in[7];
  const float* qb  = (const float*)d_in[8];
  const float* kw  = (const float*)d_in[9];
  const float* kb  = (const float*)d_in[10];
  const float* vw  = (const float*)d_in[11];
  const float* vb  = (const float*)d_in[12];
  const float* ow  = (const float*)d_in[13];
  const float* ob  = (const float*)d_in[14];
  const float* rpe = (const float*)d_in[15];
  float* out = (float*)d_out;
  float* pos_out = out + 10485760;
  float* ref_out = out + 10518528;

  char* base = (char*)d_ws;
  size_t off = 0;
  auto take = [&](size_t bytes) {
    char* pch = base + off;
    off = (off + bytes + 255) & ~(size_t)255;
    return pch;
  };
  float* pos   = (float*)take(131072);        // [128][128][2] f32
  short* x_t   = (short*)take(20971520);      // [32][512][640] bf16
  short* y_t   = (short*)take(20971520);      // [32][512][640] bf16
  short* q_t   = (short*)take(20971520);      // [32][512][640] bf16
  short* qw_bf = (short*)take(819200);
  short* kw_bf = (short*)take(819200);
  short* vw_bf = (short*)take(819200);
  short* ow_bf = (short*)take(819200);
  short* xs_bf = (short*)take(5242880);       // [32][128][640] bf16
  short* k_t   = (short*)take(5242880);       // [32][128][640] bf16
  short* v_bf  = (short*)take(5242880);       // [32][640][128] bf16
  char*  regB  = take(20971520);              // co (f32 [128][128][320]) then ao_t
  float* co    = (float*)regB;
  short* ao_t  = (short*)regB;                // [32][512][640] bf16

  // transposes + weight converts
  transpose_k<<<dim3(20, 16, 32), dim3(32, 8), 0, stream>>>(x, x_t);
  transpose_k<<<dim3(20, 16, 32), dim3(32, 8), 0, stream>>>(y, y_t);
  cvt_k<<<1600, 256, 0, stream>>>(qw, qw_bf, 409600);
  cvt_k<<<1600, 256, 0, stream>>>(kw, kw_bf, 409600);
  cvt_k<<<1600, 256, 0, stream>>>(vw, vw_bf, 409600);
  cvt_k<<<1600, 256, 0, stream>>>(ow, ow_bf, 409600);

  // offset network
  conv_off_k<<<dim3(40, 128), 256, 0, stream>>>(x, y, w1, b1, co);
  ln_proj_k<<<dim3(32, 128), 256, 0, stream>>>(co, lng, lnb, w2, pos, pos_out, ref_out);

  // deformable sampling
  sample_k<<<dim3(16, 128), 256, 0, stream>>>(x_t, pos, xs_bf);

  // projections (all [row][K] GEMMs)
  gemm_k<true,  false><<<dim3(8, 10, 32), 256, 0, stream>>>(y_t, 512LL * 640, qw_bf, 0LL, qb, q_t, 512, 640, 640);
  gemm_k<true,  false><<<dim3(2, 10, 32), 256, 0, stream>>>(xs_bf, 128LL * 640, kw_bf, 0LL, kb, k_t, 128, 640, 640);
  gemm_k<false, false><<<dim3(10, 2, 32), 256, 0, stream>>>(vw_bf, 0LL, xs_bf, 128LL * 640, vb, v_bf, 640, 640, 128);

  // fused attention (QK^T + bias + softmax + PV)
  qkpv_k<<<dim3(8, 256), 256, 0, stream>>>(q_t, k_t, v_bf, pos, rpe, ao_t);

  // output projection (f32 out)
  gemm_k<false, true><<<dim3(10, 8, 32), 256, 0, stream>>>(ow_bf, 0LL, ao_t, 512LL * 640, ob, out, 640, 640, 512);
}